// Round 9
// baseline (269.282 us; speedup 1.0000x reference)
//
#include <hip/hip_runtime.h>
#include <math.h>

#define NNODES 100000
#define NEDGES 1600000
#define DIM 64
#define TAU 0.5f
#define EPSF 1e-12f
#define SEPS 1e-6f

#define K 256                           // buckets
#define RPB 391                         // rows per bucket (391*256 >= 100000)
#define TILE 4096                       // edges per k_bin block
#define EPT 16                          // edges per thread in k_bin
#define CAP 7168                        // bucket arena stride (mean 6256, +11.6 sigma)
#define MAXK_GRID 512                   // k_maxk blocks (512 atomics total)

typedef unsigned long long ull;
typedef unsigned short u16;
typedef __attribute__((ext_vector_type(8))) short bf16x8;
typedef __attribute__((ext_vector_type(4))) float f32x4;

__device__ __forceinline__ float bf2f(u16 h) {
    return __uint_as_float((unsigned)h << 16);
}
__device__ __forceinline__ u16 f2bf(float f) {
    unsigned u = __float_as_uint(f);
    u += 0x7FFFu + ((u >> 16) & 1);  // round-to-nearest-even
    return (u16)(u >> 16);
}

// ---- init: bucket cursors to static arena bases (b*CAP) ----
__global__ __launch_bounds__(256) void k_init(int* __restrict__ bcur) {
    bcur[threadIdx.x] = threadIdx.x * CAP;
}

// ---- binning: register-staged; one global read of (r,c,w); records
//      {w:32 | lrow:9 | col:17} bucket-sorted into LDS; cooperative flush
//      into statically-strided bucket arenas (reservation via bcur). ----
__global__ __launch_bounds__(256) void k_bin(const int* __restrict__ ei, const float* __restrict__ w,
                                             int* __restrict__ bcur, ull* __restrict__ arena,
                                             int E, int N) {
    __shared__ ull stg[TILE];
    __shared__ unsigned char bkt[TILE];
    __shared__ int cnt[K], lscan[K], gbase[K], cur[K], sc[K];
    __shared__ int tot;
    int t = threadIdx.x;
    int e0 = blockIdx.x * TILE;
    cnt[t] = 0; cur[t] = 0;
    __syncthreads();
    ull rec[EPT];
    int bb[EPT];
#pragma unroll
    for (int j = 0; j < EPT; j++) {  // 48 independent loads in flight
        int e = e0 + t + j * 256;
        bb[j] = -1;
        if (e < E) {
            int r = min(max(ei[e], 0), N - 1);
            int c = min(max(ei[E + e], 0), N - 1);
            float wv = w[e];
            int b = r / RPB, lr = r - b * RPB;
            rec[j] = ((ull)__float_as_uint(wv) << 32) | (unsigned)(c | (lr << 17));
            bb[j] = b;
            atomicAdd(&cnt[b], 1);
        }
    }
    __syncthreads();
    int v = cnt[t];
    sc[t] = v;
    __syncthreads();
    for (int o = 1; o < K; o <<= 1) {
        int a = (t >= o) ? sc[t - o] : 0;
        __syncthreads();
        sc[t] += a;
        __syncthreads();
    }
    lscan[t] = sc[t] - v;
    if (v > 0) gbase[t] = atomicAdd(&bcur[t], v);  // one reservation per (block,bucket)
    if (t == K - 1) tot = sc[t];
    __syncthreads();
#pragma unroll
    for (int j = 0; j < EPT; j++) {
        if (bb[j] >= 0) {
            int p = lscan[bb[j]] + atomicAdd(&cur[bb[j]], 1);
            stg[p] = rec[j];
            bkt[p] = (unsigned char)bb[j];
        }
    }
    __syncthreads();
    // cooperative flush: all threads stream bucket-sorted records; contiguous
    // per-bucket runs keep wave writes mostly coalesced. Overflow-guarded.
    int T = tot;
    for (int i = t; i < T; i += 256) {
        int b = bkt[i];
        size_t pos = (size_t)gbase[b] + (i - lscan[b]);
        if (pos < (size_t)(b + 1) * CAP) arena[pos] = stg[i];
    }
}

// ---- per-bucket counting sort (one block per bucket, all in LDS).
//      Row-sorted records keep {lrow:9 | col:17} in .x so later passes know
//      the row without an offset search. ----
__global__ __launch_bounds__(256) void k_sort(const int* __restrict__ bcur,
                                              ull* __restrict__ arena,
                                              float* __restrict__ invdeg,
                                              int* __restrict__ off, int* __restrict__ degi,
                                              int N) {
    __shared__ ull stg[CAP];
    __shared__ int hist[RPB];     // counts, then reused as local exclusive scan
    __shared__ float degl[RPB];
    __shared__ int cur[RPB];
    __shared__ int sc[512];
    int t = threadIdx.x, b = blockIdx.x;
    int base = b * CAP;
    int cnt = min(bcur[b] - base, CAP);
    for (int i = t; i < RPB; i += 256) { hist[i] = 0; degl[i] = 0.0f; cur[i] = 0; }
    __syncthreads();
    for (int i = t; i < cnt; i += 256) {
        ull rec = arena[base + i];
        stg[i] = rec;
        int lr = (int)((rec >> 17) & 0x1FF);
        atomicAdd(&hist[lr], 1);
        atomicAdd(&degl[lr], __uint_as_float((unsigned)(rec >> 32)));
    }
    __syncthreads();
    // 512-wide Hillis-Steele scan with 2 elements/thread
    int v0 = (t < RPB) ? hist[t] : 0;
    int v1 = (t + 256 < RPB) ? hist[t + 256] : 0;
    sc[t] = v0; sc[t + 256] = v1;
    __syncthreads();
    for (int o = 1; o < 512; o <<= 1) {
        int a = (t >= o) ? sc[t - o] : 0;
        int c2 = (t + 256 >= o) ? sc[t + 256 - o] : 0;
        __syncthreads();
        sc[t] += a; sc[t + 256] += c2;
        __syncthreads();
    }
    int ex0 = sc[t] - v0, ex1 = sc[t + 256] - v1;
    hist[t] = ex0;                       // reuse hist as lscan
    if (t + 256 < RPB) hist[t + 256] = ex1;
    int rn0 = b * RPB + t;
    if (rn0 < N) {
        off[rn0] = base + ex0; degi[rn0] = v0;
        invdeg[rn0] = 1.0f / fmaxf(degl[t], EPSF);
    }
    int rn1 = rn0 + 256;
    if (t + 256 < RPB && rn1 < N) {
        off[rn1] = base + ex1; degi[rn1] = v1;
        invdeg[rn1] = 1.0f / fmaxf(degl[t + 256], EPSF);
    }
    __syncthreads();
    // scatter in place; keep low 26 bits {lr<<17 | col} in .x
    int2* out2 = (int2*)arena;
    for (int i = t; i < cnt; i += 256) {
        ull rec = stg[i];
        int lr = (int)((rec >> 17) & 0x1FF);
        int p = hist[lr] + atomicAdd(&cur[lr], 1);
        out2[base + p] = make_int2((int)(rec & 0x3FFFFFF), (int)(unsigned)(rec >> 32));
    }
}

// ---- max|kappa|: grid-stride edge scan; ONE atomic per block (512 total). ----
__global__ __launch_bounds__(256) void k_maxk(const int* __restrict__ ei,
                                              const float* __restrict__ invdeg,
                                              float* __restrict__ maxabs, int E, int N) {
    float m = 0.0f;
    int stride = gridDim.x * 256;
    for (int e = blockIdx.x * 256 + threadIdx.x; e < E; e += stride) {
        int r = min(max(ei[e], 0), N - 1);
        int c = min(max(ei[E + e], 0), N - 1);
        m = fmaxf(m, fabsf(2.0f * invdeg[r] + 2.0f * invdeg[c] - 2.0f));
    }
    for (int o = 32; o > 0; o >>= 1) m = fmaxf(m, __shfl_down(m, o, 64));
    __shared__ float red[4];
    int lane = threadIdx.x & 63, wid = threadIdx.x >> 6;
    if (lane == 0) red[wid] = m;
    __syncthreads();
    if (threadIdx.x == 0) {
        float bm = fmaxf(fmaxf(red[0], red[1]), fmaxf(red[2], red[3]));
        atomicMax((unsigned int*)maxabs, __float_as_uint(bm));  // non-negative floats
    }
}

// ---- wh pass: one block per bucket, csr-position-indexed (COALESCED).
//      Streams csr, computes kap/wh, writes wh back into csr.y (full-line
//      sequential 8B stores), LDS row-reduction -> rho, row_sum.
//      Replaces per-node k_node (strided) AND frees k_aggr of wh VALU. ----
__global__ __launch_bounds__(256) void k_wh(const int* __restrict__ bcur,
                                            const float* __restrict__ invdeg,
                                            int2* __restrict__ csr,
                                            const float* __restrict__ maxabs,
                                            float* __restrict__ rho,
                                            float* __restrict__ row_sum, int N) {
    __shared__ float ivl[RPB], rs[RPB], ks[RPB];
    __shared__ int ct[RPB];
    int t = threadIdx.x, b = blockIdx.x;
    int base = b * CAP;
    int cnt = min(bcur[b] - base, CAP);
    int r0 = b * RPB;
    for (int i = t; i < RPB; i += 256) {
        int rn = r0 + i;
        ivl[i] = (rn < N) ? invdeg[rn] : 0.0f;
        rs[i] = 0.0f; ks[i] = 0.0f; ct[i] = 0;
    }
    __syncthreads();
    float dt = 0.5f / (*maxabs + 1e-6f);
    for (int i = t; i < cnt; i += 256) {
        int2 rec = csr[base + i];
        int col = rec.x & 0x1FFFF;
        int lr = rec.x >> 17;            // bits 17..25, always >= 0
        float kap = 2.0f * (ivl[lr] + invdeg[col]) - 2.0f;
        float wh = fmaxf(__int_as_float(rec.y) * (1.0f - 0.5f * dt * kap), 0.0f);
        if (wh > SEPS) {
            atomicAdd(&rs[lr], wh);
            atomicAdd(&ks[lr], kap);
            atomicAdd(&ct[lr], 1);
        } else {
            wh = 0.0f;
        }
        csr[base + i] = make_int2(rec.x, __float_as_int(wh));
    }
    __syncthreads();
    for (int i = t; i < RPB; i += 256) {
        int rn = r0 + i;
        if (rn < N) {
            float mk = ks[i] / fmaxf((float)ct[i], 1.0f);
            rho[rn] = 1.0f / (1.0f + expf(-mk));
            row_sum[rn] = rs[i];
        }
    }
}

// ---- MFMA GEMM: hneigh = x@Wn^T (bf16 store); out = rho*(x@Ws^T) + TAU*x.
//      Split-bf16 (hi+lo) operands -> fp32-class accuracy with 3 MFMAs/term. ----
#define WL(mp, d, kk) (((mp) * 64 + (d)) * 72 + (kk))
__global__ __launch_bounds__(256) void k_gemm(const float* __restrict__ x,
                                              const float* __restrict__ Wself,
                                              const float* __restrict__ Wneigh,
                                              const float* __restrict__ rho,
                                              u16* __restrict__ hneigh_h,
                                              float* __restrict__ out, int N) {
    __shared__ u16 wlds[4 * 64 * 72];   // [mat*2+part][64][72], 36.9 KB
    int t = threadIdx.x;
    for (int i = t; i < 4096; i += 256) {
        int d = i >> 6, k = i & 63;
        float v = Wself[i];
        u16 h = f2bf(v);
        u16 lo = f2bf(v - bf2f(h));      // exact residual (Sterbenz)
        wlds[WL(0, d, k)] = h;
        wlds[WL(1, d, k)] = lo;
        v = Wneigh[i];
        h = f2bf(v);
        lo = f2bf(v - bf2f(h));
        wlds[WL(2, d, k)] = h;
        wlds[WL(3, d, k)] = lo;
    }
    __syncthreads();
    int w = t >> 6, l = t & 63;
    int m = l & 15, kg = l >> 4;         // A row / B col = m; k-group = kg
    int n0 = blockIdx.x * 64 + w * 16;
    if (n0 >= N) return;                 // whole-wave OOB (no barriers below)
    int nodeA = n0 + m;
    // A fragments: x row nodeA, 8 contiguous k per lane, split hi/lo
    bf16x8 ah[2], al[2];
#pragma unroll
    for (int ks = 0; ks < 2; ks++) {
        float v[8];
        if (nodeA < N) {
            const float4* xp = (const float4*)(x + (size_t)nodeA * 64 + ks * 32 + kg * 8);
            float4 v0 = xp[0], v1 = xp[1];
            v[0] = v0.x; v[1] = v0.y; v[2] = v0.z; v[3] = v0.w;
            v[4] = v1.x; v[5] = v1.y; v[6] = v1.z; v[7] = v1.w;
        } else {
#pragma unroll
            for (int j = 0; j < 8; j++) v[j] = 0.0f;
        }
#pragma unroll
        for (int j = 0; j < 8; j++) {
            u16 h = f2bf(v[j]);
            u16 lo = f2bf(v[j] - bf2f(h));
            ah[ks][j] = (short)h;
            al[ks][j] = (short)lo;
        }
    }
    f32x4 accS[4], accN[4];
#pragma unroll
    for (int dt = 0; dt < 4; dt++) {
        accS[dt] = (f32x4){0.0f, 0.0f, 0.0f, 0.0f};
        accN[dt] = (f32x4){0.0f, 0.0f, 0.0f, 0.0f};
    }
#pragma unroll
    for (int dt = 0; dt < 4; dt++) {
        int d = dt * 16 + m;
#pragma unroll
        for (int ks = 0; ks < 2; ks++) {
            int kof = ks * 32 + kg * 8;
            bf16x8 bsh = *(const bf16x8*)&wlds[WL(0, d, kof)];
            bf16x8 bsl = *(const bf16x8*)&wlds[WL(1, d, kof)];
            bf16x8 bnh = *(const bf16x8*)&wlds[WL(2, d, kof)];
            bf16x8 bnl = *(const bf16x8*)&wlds[WL(3, d, kof)];
            accS[dt] = __builtin_amdgcn_mfma_f32_16x16x32_bf16(ah[ks], bsh, accS[dt], 0, 0, 0);
            accS[dt] = __builtin_amdgcn_mfma_f32_16x16x32_bf16(al[ks], bsh, accS[dt], 0, 0, 0);
            accS[dt] = __builtin_amdgcn_mfma_f32_16x16x32_bf16(ah[ks], bsl, accS[dt], 0, 0, 0);
            accN[dt] = __builtin_amdgcn_mfma_f32_16x16x32_bf16(ah[ks], bnh, accN[dt], 0, 0, 0);
            accN[dt] = __builtin_amdgcn_mfma_f32_16x16x32_bf16(al[ks], bnh, accN[dt], 0, 0, 0);
            accN[dt] = __builtin_amdgcn_mfma_f32_16x16x32_bf16(ah[ks], bnl, accN[dt], 0, 0, 0);
        }
    }
    // epilogue: C row = kg*4 + r (node), col = m (dim within d-tile)
    int rbase = kg * 4;
#pragma unroll
    for (int r = 0; r < 4; r++) {
        int nn = n0 + rbase + r;
        if (nn >= N) continue;
        float rh = rho[nn];
#pragma unroll
        for (int dt = 0; dt < 4; dt++) {
            int d = dt * 16 + m;
            size_t idx = (size_t)nn * 64 + d;
            out[idx] = rh * accS[dt][r] + TAU * x[idx];
            hneigh_h[idx] = f2bf(accN[dt][r]);
        }
    }
}

// ---- neighbor aggregation: wave per node; csr.y holds masked wh (k_wh).
//      16-lane sub-groups: lane = g*16+q handles dims 4q..4q+3 of edge (i+g);
//      ushort4 gathers; 16-edge main loop keeps 4 gathers in flight. ----
__global__ __launch_bounds__(256) void k_aggr(const int* __restrict__ off,
                                              const int* __restrict__ degi,
                                              const int2* __restrict__ csr,
                                              const float* __restrict__ row_sum,
                                              const u16* __restrict__ hneigh_h,
                                              float* __restrict__ out, int N) {
    int t = threadIdx.x;
    int lane = t & 63;
    int q = lane & 15;        // dim quad: dims 4q..4q+3
    int g = lane >> 4;        // edge sub-group 0..3
    int n = blockIdx.x * 4 + (t >> 6);
    if (n >= N) return;
    int s = off[n], end = s + degi[n];
    float inv_rs = 1.0f / fmaxf(row_sum[n], EPSF);
    const ushort4* hn4 = (const ushort4*)hneigh_h;
    float a0 = 0.0f, a1 = 0.0f, a2 = 0.0f, a3 = 0.0f;
    int i = s;
    for (; i + 16 <= end; i += 16) {  // 4 packets: 4 gathers in flight
        int2 p0 = csr[i + g];
        int2 p1 = csr[i + 4 + g];
        int2 p2 = csr[i + 8 + g];
        int2 p3 = csr[i + 12 + g];
        ushort4 h0 = hn4[(unsigned)(((p0.x & 0x1FFFF) << 4) | q)];
        ushort4 h1 = hn4[(unsigned)(((p1.x & 0x1FFFF) << 4) | q)];
        ushort4 h2 = hn4[(unsigned)(((p2.x & 0x1FFFF) << 4) | q)];
        ushort4 h3 = hn4[(unsigned)(((p3.x & 0x1FFFF) << 4) | q)];
        float w0 = __int_as_float(p0.y), w1 = __int_as_float(p1.y);
        float w2 = __int_as_float(p2.y), w3 = __int_as_float(p3.y);
        a0 = fmaf(w0, bf2f(h0.x), a0); a1 = fmaf(w0, bf2f(h0.y), a1);
        a2 = fmaf(w0, bf2f(h0.z), a2); a3 = fmaf(w0, bf2f(h0.w), a3);
        a0 = fmaf(w1, bf2f(h1.x), a0); a1 = fmaf(w1, bf2f(h1.y), a1);
        a2 = fmaf(w1, bf2f(h1.z), a2); a3 = fmaf(w1, bf2f(h1.w), a3);
        a0 = fmaf(w2, bf2f(h2.x), a0); a1 = fmaf(w2, bf2f(h2.y), a1);
        a2 = fmaf(w2, bf2f(h2.z), a2); a3 = fmaf(w2, bf2f(h2.w), a3);
        a0 = fmaf(w3, bf2f(h3.x), a0); a1 = fmaf(w3, bf2f(h3.y), a1);
        a2 = fmaf(w3, bf2f(h3.z), a2); a3 = fmaf(w3, bf2f(h3.w), a3);
    }
    for (; i + 8 <= end; i += 8) {  // 2 packets
        int2 p0 = csr[i + g];
        int2 p1 = csr[i + 4 + g];
        ushort4 h0 = hn4[(unsigned)(((p0.x & 0x1FFFF) << 4) | q)];
        ushort4 h1 = hn4[(unsigned)(((p1.x & 0x1FFFF) << 4) | q)];
        float w0 = __int_as_float(p0.y), w1 = __int_as_float(p1.y);
        a0 = fmaf(w0, bf2f(h0.x), a0); a1 = fmaf(w0, bf2f(h0.y), a1);
        a2 = fmaf(w0, bf2f(h0.z), a2); a3 = fmaf(w0, bf2f(h0.w), a3);
        a0 = fmaf(w1, bf2f(h1.x), a0); a1 = fmaf(w1, bf2f(h1.y), a1);
        a2 = fmaf(w1, bf2f(h1.z), a2); a3 = fmaf(w1, bf2f(h1.w), a3);
    }
    for (; i < end; i += 4) {  // predicated tail, 4 edges/iter
        int e = i + g;
        bool v = e < end;
        int2 p = make_int2(0, 0);
        if (v) p = csr[e];
        ushort4 h = hn4[(unsigned)(((p.x & 0x1FFFF) << 4) | q)];  // col 0 safe when masked
        float wv = v ? __int_as_float(p.y) : 0.0f;
        a0 = fmaf(wv, bf2f(h.x), a0);
        a1 = fmaf(wv, bf2f(h.y), a1);
        a2 = fmaf(wv, bf2f(h.z), a2);
        a3 = fmaf(wv, bf2f(h.w), a3);
    }
    // combine the 4 edge-group partials (lanes differing in bits 4,5 share q)
    a0 += __shfl_xor(a0, 16, 64);
    a1 += __shfl_xor(a1, 16, 64);
    a2 += __shfl_xor(a2, 16, 64);
    a3 += __shfl_xor(a3, 16, 64);
    a0 += __shfl_xor(a0, 32, 64);
    a1 += __shfl_xor(a1, 32, 64);
    a2 += __shfl_xor(a2, 32, 64);
    a3 += __shfl_xor(a3, 32, 64);
    if (g == 0) {  // unique owner, non-atomic RMW; quarter-wave float4 store
        float4* o4 = (float4*)(out + (size_t)n * 64);
        float4 o = o4[q];
        o.x += a0 * inv_rs;
        o.y += a1 * inv_rs;
        o.z += a2 * inv_rs;
        o.w += a3 * inv_rs;
        o4[q] = o;
    }
}

// ---- final e-indexed pass: w_norm (coalesced) + edge_index->float, fused ----
__global__ void k_final(const int* __restrict__ ei, const float* __restrict__ w,
                        const float* __restrict__ invdeg, const float* __restrict__ row_sum,
                        const float* __restrict__ maxabs,
                        float* __restrict__ out_ei, float* __restrict__ out_wn, int E, int N) {
    int e = blockIdx.x * blockDim.x + threadIdx.x;
    if (e >= E) return;
    int r0 = ei[e], c0 = ei[E + e];
    int r = min(max(r0, 0), N - 1);
    int c = min(max(c0, 0), N - 1);
    float dt = 0.5f / (*maxabs + 1e-6f);
    float kap = 2.0f * invdeg[r] + 2.0f * invdeg[c] - 2.0f;
    float wh = fmaxf(w[e] * (1.0f - 0.5f * dt * kap), 0.0f);
    if (wh <= SEPS) wh = 0.0f;
    out_wn[e] = wh / fmaxf(row_sum[r], EPSF);
    out_ei[e] = (float)r0;
    out_ei[E + e] = (float)c0;
}

extern "C" void kernel_launch(void* const* d_in, const int* in_sizes, int n_in,
                              void* d_out, int out_size, void* d_ws, size_t ws_size,
                              hipStream_t stream) {
    (void)in_sizes; (void)n_in; (void)out_size; (void)ws_size;
    const int N = NNODES, E = NEDGES;

    const float* x      = (const float*)d_in[0];
    const int*   ei     = (const int*)d_in[1];
    const float* w      = (const float*)d_in[2];
    const float* Wself  = (const float*)d_in[3];
    const float* Wneigh = (const float*)d_in[4];

    float* out    = (float*)d_out;           // [N*64]
    float* out_ei = out + (size_t)N * DIM;   // [2E] edge_index as float (final)
    float* out_wn = out_ei + 2 * (size_t)E;  // [E]  w_norm (final)

    // Statically CAP-strided bucket arena staged in out_ei/out_wn region
    // (256*7168*8B = 14.7 MB < 19.2 MB; dead until k_final overwrites it)
    ull*  arena = (ull*)out_ei;    // k_bin output: packed records
    int2* csr   = (int2*)out_ei;   // k_sort: {lr<<17|col, w}; k_wh: {.., wh}

    // ws layout (floats): invdeg[N] | off[N] | degi[N] | rho[N] | row_sum[N] |
    // maxabs[4] | bcur[256] | pad-to-128B | hneigh_h u16[64N]
    // hneigh_h byte offset = (5N + 288)*4 = 2,001,152 = 128*15634  (128B-ALIGNED:
    // a 64B-misaligned hneigh_h doubles gather FETCH, 99.6->178 MB, R7 lesson)
    float* invdeg  = (float*)d_ws;
    int*   off     = (int*)d_ws + (size_t)N;
    int*   degi    = (int*)d_ws + 2 * (size_t)N;
    float* rho     = (float*)d_ws + 3 * (size_t)N;
    float* row_sum = rho + (size_t)N;
    float* maxabs  = row_sum + (size_t)N;            // 5N
    int*   bcur    = (int*)(maxabs + 4);
    u16*   hneigh_h = (u16*)((float*)d_ws + 5 * (size_t)N + 288);

    hipMemsetAsync((void*)maxabs, 0, 4 * sizeof(float), stream);

    k_init<<<1, 256, 0, stream>>>(bcur);
    k_bin<<<(E + TILE - 1) / TILE, 256, 0, stream>>>(ei, w, bcur, arena, E, N);
    k_sort<<<K, 256, 0, stream>>>(bcur, arena, invdeg, off, degi, N);
    k_maxk<<<MAXK_GRID, 256, 0, stream>>>(ei, invdeg, maxabs, E, N);
    k_wh<<<K, 256, 0, stream>>>(bcur, invdeg, csr, maxabs, rho, row_sum, N);
    k_gemm<<<(N + 63) / 64, 256, 0, stream>>>(x, Wself, Wneigh, rho, hneigh_h, out, N);
    k_aggr<<<(N + 3) / 4, 256, 0, stream>>>(off, degi, csr, row_sum, hneigh_h, out, N);
    k_final<<<(E + 255) / 256, 256, 0, stream>>>(ei, w, invdeg, row_sum, maxabs,
                                                 out_ei, out_wn, E, N);
}

// Round 10
// 249.434 us; speedup vs baseline: 1.0796x; 1.0796x over previous
//
#include <hip/hip_runtime.h>
#include <math.h>

#define NNODES 100000
#define NEDGES 1600000
#define DIM 64
#define TAU 0.5f
#define EPSF 1e-12f
#define SEPS 1e-6f

#define K 256                           // buckets
#define RPB 391                         // rows per bucket (391*256 >= 100000)
#define TILE 4096                       // edges per k_bin block
#define EPT 16                          // edges per thread in k_bin
#define CAP 7168                        // bucket arena stride (mean 6256, +11.6 sigma)
#define MAXK_GRID 512                   // k_maxk blocks (512 atomics total)

typedef unsigned long long ull;
typedef unsigned short u16;
typedef __attribute__((ext_vector_type(8))) short bf16x8;
typedef __attribute__((ext_vector_type(4))) float f32x4;

__device__ __forceinline__ float bf2f(u16 h) {
    return __uint_as_float((unsigned)h << 16);
}
__device__ __forceinline__ u16 f2bf(float f) {
    unsigned u = __float_as_uint(f);
    u += 0x7FFFu + ((u >> 16) & 1);  // round-to-nearest-even
    return (u16)(u >> 16);
}

// ---- init: bucket cursors to static arena bases (b*CAP); zero maxabs ----
__global__ __launch_bounds__(256) void k_init(int* __restrict__ bcur,
                                              float* __restrict__ maxabs) {
    bcur[threadIdx.x] = threadIdx.x * CAP;
    if (threadIdx.x < 4) maxabs[threadIdx.x] = 0.0f;
}

// ---- binning: register-staged; one global read of (r,c,w); records
//      {w:32 | lrow:9 | col:17} bucket-sorted into LDS; cooperative flush
//      into statically-strided bucket arenas (reservation via bcur). ----
__global__ __launch_bounds__(256) void k_bin(const int* __restrict__ ei, const float* __restrict__ w,
                                             int* __restrict__ bcur, ull* __restrict__ arena,
                                             int E, int N) {
    __shared__ ull stg[TILE];
    __shared__ unsigned char bkt[TILE];
    __shared__ int cnt[K], lscan[K], gbase[K], cur[K], sc[K];
    __shared__ int tot;
    int t = threadIdx.x;
    int e0 = blockIdx.x * TILE;
    cnt[t] = 0; cur[t] = 0;
    __syncthreads();
    ull rec[EPT];
    int bb[EPT];
#pragma unroll
    for (int j = 0; j < EPT; j++) {  // 48 independent loads in flight
        int e = e0 + t + j * 256;
        bb[j] = -1;
        if (e < E) {
            int r = min(max(ei[e], 0), N - 1);
            int c = min(max(ei[E + e], 0), N - 1);
            float wv = w[e];
            int b = r / RPB, lr = r - b * RPB;
            rec[j] = ((ull)__float_as_uint(wv) << 32) | (unsigned)(c | (lr << 17));
            bb[j] = b;
            atomicAdd(&cnt[b], 1);
        }
    }
    __syncthreads();
    int v = cnt[t];
    sc[t] = v;
    __syncthreads();
    for (int o = 1; o < K; o <<= 1) {
        int a = (t >= o) ? sc[t - o] : 0;
        __syncthreads();
        sc[t] += a;
        __syncthreads();
    }
    lscan[t] = sc[t] - v;
    if (v > 0) gbase[t] = atomicAdd(&bcur[t], v);  // one reservation per (block,bucket)
    if (t == K - 1) tot = sc[t];
    __syncthreads();
#pragma unroll
    for (int j = 0; j < EPT; j++) {
        if (bb[j] >= 0) {
            int p = lscan[bb[j]] + atomicAdd(&cur[bb[j]], 1);
            stg[p] = rec[j];
            bkt[p] = (unsigned char)bb[j];
        }
    }
    __syncthreads();
    // cooperative flush: all threads stream bucket-sorted records; contiguous
    // per-bucket runs keep wave writes mostly coalesced. Overflow-guarded.
    int T = tot;
    for (int i = t; i < T; i += 256) {
        int b = bkt[i];
        size_t pos = (size_t)gbase[b] + (i - lscan[b]);
        if (pos < (size_t)(b + 1) * CAP) arena[pos] = stg[i];
    }
}

// ---- per-bucket counting sort (one block per bucket, all in LDS).
//      Computes deg per row -> invdeg[], off[], degi[], row-sorted {col,w}. ----
__global__ __launch_bounds__(256) void k_sort(const int* __restrict__ bcur,
                                              ull* __restrict__ arena,
                                              float* __restrict__ invdeg,
                                              int* __restrict__ off, int* __restrict__ degi,
                                              int N) {
    __shared__ ull stg[CAP];
    __shared__ int hist[RPB];     // counts, then reused as local exclusive scan
    __shared__ float degl[RPB];
    __shared__ int cur[RPB];
    __shared__ int sc[512];
    int t = threadIdx.x, b = blockIdx.x;
    int base = b * CAP;
    int cnt = min(bcur[b] - base, CAP);
    for (int i = t; i < RPB; i += 256) { hist[i] = 0; degl[i] = 0.0f; cur[i] = 0; }
    __syncthreads();
    for (int i = t; i < cnt; i += 256) {
        ull rec = arena[base + i];
        stg[i] = rec;
        int lr = (int)((rec >> 17) & 0x1FF);
        atomicAdd(&hist[lr], 1);
        atomicAdd(&degl[lr], __uint_as_float((unsigned)(rec >> 32)));
    }
    __syncthreads();
    // 512-wide Hillis-Steele scan with 2 elements/thread
    int v0 = (t < RPB) ? hist[t] : 0;
    int v1 = (t + 256 < RPB) ? hist[t + 256] : 0;
    sc[t] = v0; sc[t + 256] = v1;
    __syncthreads();
    for (int o = 1; o < 512; o <<= 1) {
        int a = (t >= o) ? sc[t - o] : 0;
        int c2 = (t + 256 >= o) ? sc[t + 256 - o] : 0;
        __syncthreads();
        sc[t] += a; sc[t + 256] += c2;
        __syncthreads();
    }
    int ex0 = sc[t] - v0, ex1 = sc[t + 256] - v1;
    hist[t] = ex0;                       // reuse hist as lscan
    if (t + 256 < RPB) hist[t + 256] = ex1;
    int rn0 = b * RPB + t;
    if (rn0 < N) {
        off[rn0] = base + ex0; degi[rn0] = v0;
        invdeg[rn0] = 1.0f / fmaxf(degl[t], EPSF);
    }
    int rn1 = rn0 + 256;
    if (t + 256 < RPB && rn1 < N) {
        off[rn1] = base + ex1; degi[rn1] = v1;
        invdeg[rn1] = 1.0f / fmaxf(degl[t + 256], EPSF);
    }
    __syncthreads();
    // scatter in place (writes land in this block's hot ~50KB L2 region)
    int2* out2 = (int2*)arena;
    for (int i = t; i < cnt; i += 256) {
        ull rec = stg[i];
        int lr = (int)((rec >> 17) & 0x1FF);
        int p = hist[lr] + atomicAdd(&cur[lr], 1);
        out2[base + p] = make_int2((int)(rec & 0x1FFFF), (int)(unsigned)(rec >> 32));
    }
}

// ---- max|kappa|: grid-stride edge scan; ONE atomic per block (512 total). ----
__global__ __launch_bounds__(256) void k_maxk(const int* __restrict__ ei,
                                              const float* __restrict__ invdeg,
                                              float* __restrict__ maxabs, int E, int N) {
    float m = 0.0f;
    int stride = gridDim.x * 256;
    for (int e = blockIdx.x * 256 + threadIdx.x; e < E; e += stride) {
        int r = min(max(ei[e], 0), N - 1);
        int c = min(max(ei[E + e], 0), N - 1);
        m = fmaxf(m, fabsf(2.0f * invdeg[r] + 2.0f * invdeg[c] - 2.0f));
    }
    for (int o = 32; o > 0; o >>= 1) m = fmaxf(m, __shfl_down(m, o, 64));
    __shared__ float red[4];
    int lane = threadIdx.x & 63, wid = threadIdx.x >> 6;
    if (lane == 0) red[wid] = m;
    __syncthreads();
    if (threadIdx.x == 0) {
        float bm = fmaxf(fmaxf(red[0], red[1]), fmaxf(red[2], red[3]));
        atomicMax((unsigned int*)maxabs, __float_as_uint(bm));  // non-negative floats
    }
}

// ---- MFMA GEMM: hneigh = x@Wn^T (bf16 store); out = x@Ws^T RAW (rho and
//      TAU*x applied later in k_aggr). Split-bf16 hi/lo -> fp32-class. ----
#define WL(mp, d, kk) (((mp) * 64 + (d)) * 72 + (kk))
__global__ __launch_bounds__(256) void k_gemm(const float* __restrict__ x,
                                              const float* __restrict__ Wself,
                                              const float* __restrict__ Wneigh,
                                              u16* __restrict__ hneigh_h,
                                              float* __restrict__ out, int N) {
    __shared__ u16 wlds[4 * 64 * 72];   // [mat*2+part][64][72], 36.9 KB
    int t = threadIdx.x;
    for (int i = t; i < 4096; i += 256) {
        int d = i >> 6, k = i & 63;
        float v = Wself[i];
        u16 h = f2bf(v);
        u16 lo = f2bf(v - bf2f(h));      // exact residual (Sterbenz)
        wlds[WL(0, d, k)] = h;
        wlds[WL(1, d, k)] = lo;
        v = Wneigh[i];
        h = f2bf(v);
        lo = f2bf(v - bf2f(h));
        wlds[WL(2, d, k)] = h;
        wlds[WL(3, d, k)] = lo;
    }
    __syncthreads();
    int w = t >> 6, l = t & 63;
    int m = l & 15, kg = l >> 4;         // A row / B col = m; k-group = kg
    int n0 = blockIdx.x * 64 + w * 16;
    if (n0 >= N) return;                 // whole-wave OOB (no barriers below)
    int nodeA = n0 + m;
    // A fragments: x row nodeA, 8 contiguous k per lane, split hi/lo
    bf16x8 ah[2], al[2];
#pragma unroll
    for (int ks = 0; ks < 2; ks++) {
        float v[8];
        if (nodeA < N) {
            const float4* xp = (const float4*)(x + (size_t)nodeA * 64 + ks * 32 + kg * 8);
            float4 v0 = xp[0], v1 = xp[1];
            v[0] = v0.x; v[1] = v0.y; v[2] = v0.z; v[3] = v0.w;
            v[4] = v1.x; v[5] = v1.y; v[6] = v1.z; v[7] = v1.w;
        } else {
#pragma unroll
            for (int j = 0; j < 8; j++) v[j] = 0.0f;
        }
#pragma unroll
        for (int j = 0; j < 8; j++) {
            u16 h = f2bf(v[j]);
            u16 lo = f2bf(v[j] - bf2f(h));
            ah[ks][j] = (short)h;
            al[ks][j] = (short)lo;
        }
    }
    f32x4 accS[4], accN[4];
#pragma unroll
    for (int dt = 0; dt < 4; dt++) {
        accS[dt] = (f32x4){0.0f, 0.0f, 0.0f, 0.0f};
        accN[dt] = (f32x4){0.0f, 0.0f, 0.0f, 0.0f};
    }
#pragma unroll
    for (int dt = 0; dt < 4; dt++) {
        int d = dt * 16 + m;
#pragma unroll
        for (int ks = 0; ks < 2; ks++) {
            int kof = ks * 32 + kg * 8;
            bf16x8 bsh = *(const bf16x8*)&wlds[WL(0, d, kof)];
            bf16x8 bsl = *(const bf16x8*)&wlds[WL(1, d, kof)];
            bf16x8 bnh = *(const bf16x8*)&wlds[WL(2, d, kof)];
            bf16x8 bnl = *(const bf16x8*)&wlds[WL(3, d, kof)];
            accS[dt] = __builtin_amdgcn_mfma_f32_16x16x32_bf16(ah[ks], bsh, accS[dt], 0, 0, 0);
            accS[dt] = __builtin_amdgcn_mfma_f32_16x16x32_bf16(al[ks], bsh, accS[dt], 0, 0, 0);
            accS[dt] = __builtin_amdgcn_mfma_f32_16x16x32_bf16(ah[ks], bsl, accS[dt], 0, 0, 0);
            accN[dt] = __builtin_amdgcn_mfma_f32_16x16x32_bf16(ah[ks], bnh, accN[dt], 0, 0, 0);
            accN[dt] = __builtin_amdgcn_mfma_f32_16x16x32_bf16(al[ks], bnh, accN[dt], 0, 0, 0);
            accN[dt] = __builtin_amdgcn_mfma_f32_16x16x32_bf16(ah[ks], bnl, accN[dt], 0, 0, 0);
        }
    }
    // epilogue: C row = kg*4 + r (node), col = m (dim within d-tile)
    int rbase = kg * 4;
#pragma unroll
    for (int r = 0; r < 4; r++) {
        int nn = n0 + rbase + r;
        if (nn >= N) continue;
#pragma unroll
        for (int dt = 0; dt < 4; dt++) {
            int d = dt * 16 + m;
            size_t idx = (size_t)nn * 64 + d;
            out[idx] = accS[dt][r];
            hneigh_h[idx] = f2bf(accN[dt][r]);
        }
    }
}

// ---- FUSED aggregation + node pass: wave per node. Inline wh (invdeg
//      gathers), acc fmas, AND rs/ks/ct reductions in one CSR walk.
//      rho/inv_rs derived in-register; epilogue applies
//      out = rho*h_self + TAU*x + acc*inv_rs; writes row_sum for k_final. ----
__global__ __launch_bounds__(256) void k_aggr(const int* __restrict__ off,
                                              const int* __restrict__ degi,
                                              const float* __restrict__ invdeg,
                                              const int2* __restrict__ csr,
                                              const float* __restrict__ maxabs,
                                              const float* __restrict__ x,
                                              const u16* __restrict__ hneigh_h,
                                              float* __restrict__ row_sum,
                                              float* __restrict__ out, int N) {
    int t = threadIdx.x;
    int lane = t & 63;
    int q = lane & 15;        // dim quad: dims 4q..4q+3
    int g = lane >> 4;        // edge sub-group 0..3
    int n = blockIdx.x * 4 + (t >> 6);
    if (n >= N) return;
    int s = off[n], end = s + degi[n];
    float dt = 0.5f / (*maxabs + 1e-6f);
    float c1 = -0.5f * dt;
    float a = 2.0f * invdeg[n] - 2.0f;
    const ushort4* hn4 = (const ushort4*)hneigh_h;
    float a0 = 0.0f, a1 = 0.0f, a2 = 0.0f, a3 = 0.0f;
    float rs = 0.0f, ks = 0.0f, ct = 0.0f;
    int i = s;
    for (; i + 16 <= end; i += 16) {  // 4 packets: 4 gathers in flight
        int2 p0 = csr[i + g];
        int2 p1 = csr[i + 4 + g];
        int2 p2 = csr[i + 8 + g];
        int2 p3 = csr[i + 12 + g];
        ushort4 h0 = hn4[(unsigned)((p0.x << 4) | q)];
        ushort4 h1 = hn4[(unsigned)((p1.x << 4) | q)];
        ushort4 h2 = hn4[(unsigned)((p2.x << 4) | q)];
        ushort4 h3 = hn4[(unsigned)((p3.x << 4) | q)];
        float k0 = fmaf(2.0f, invdeg[p0.x], a), k1 = fmaf(2.0f, invdeg[p1.x], a);
        float k2 = fmaf(2.0f, invdeg[p2.x], a), k3 = fmaf(2.0f, invdeg[p3.x], a);
        float w0 = __int_as_float(p0.y) * fmaf(c1, k0, 1.0f);
        float w1 = __int_as_float(p1.y) * fmaf(c1, k1, 1.0f);
        float w2 = __int_as_float(p2.y) * fmaf(c1, k2, 1.0f);
        float w3 = __int_as_float(p3.y) * fmaf(c1, k3, 1.0f);
        bool m0 = w0 > SEPS, m1 = w1 > SEPS, m2 = w2 > SEPS, m3 = w3 > SEPS;
        w0 = m0 ? w0 : 0.0f;
        w1 = m1 ? w1 : 0.0f;
        w2 = m2 ? w2 : 0.0f;
        w3 = m3 ? w3 : 0.0f;
        rs += (w0 + w1) + (w2 + w3);
        ks += ((m0 ? k0 : 0.0f) + (m1 ? k1 : 0.0f)) + ((m2 ? k2 : 0.0f) + (m3 ? k3 : 0.0f));
        ct += ((m0 ? 1.0f : 0.0f) + (m1 ? 1.0f : 0.0f)) + ((m2 ? 1.0f : 0.0f) + (m3 ? 1.0f : 0.0f));
        a0 = fmaf(w0, bf2f(h0.x), a0); a1 = fmaf(w0, bf2f(h0.y), a1);
        a2 = fmaf(w0, bf2f(h0.z), a2); a3 = fmaf(w0, bf2f(h0.w), a3);
        a0 = fmaf(w1, bf2f(h1.x), a0); a1 = fmaf(w1, bf2f(h1.y), a1);
        a2 = fmaf(w1, bf2f(h1.z), a2); a3 = fmaf(w1, bf2f(h1.w), a3);
        a0 = fmaf(w2, bf2f(h2.x), a0); a1 = fmaf(w2, bf2f(h2.y), a1);
        a2 = fmaf(w2, bf2f(h2.z), a2); a3 = fmaf(w2, bf2f(h2.w), a3);
        a0 = fmaf(w3, bf2f(h3.x), a0); a1 = fmaf(w3, bf2f(h3.y), a1);
        a2 = fmaf(w3, bf2f(h3.z), a2); a3 = fmaf(w3, bf2f(h3.w), a3);
    }
    for (; i < end; i += 4) {  // predicated tail, 4 edges/iter
        int e = i + g;
        bool v = e < end;
        int2 p = make_int2(0, 0);
        if (v) p = csr[e];
        ushort4 h = hn4[(unsigned)((p.x << 4) | q)];  // p.x==0 safe when masked
        float kk = fmaf(2.0f, invdeg[p.x], a);
        float wv = __int_as_float(p.y) * fmaf(c1, kk, 1.0f);
        bool m = v && (wv > SEPS);
        wv = m ? wv : 0.0f;
        rs += wv;
        ks += m ? kk : 0.0f;
        ct += m ? 1.0f : 0.0f;
        a0 = fmaf(wv, bf2f(h.x), a0);
        a1 = fmaf(wv, bf2f(h.y), a1);
        a2 = fmaf(wv, bf2f(h.z), a2);
        a3 = fmaf(wv, bf2f(h.w), a3);
    }
    // combine the 4 edge-group partials (bits 4,5 = g; q preserved)
    a0 += __shfl_xor(a0, 16, 64);
    a1 += __shfl_xor(a1, 16, 64);
    a2 += __shfl_xor(a2, 16, 64);
    a3 += __shfl_xor(a3, 16, 64);
    rs += __shfl_xor(rs, 16, 64);
    ks += __shfl_xor(ks, 16, 64);
    ct += __shfl_xor(ct, 16, 64);
    a0 += __shfl_xor(a0, 32, 64);
    a1 += __shfl_xor(a1, 32, 64);
    a2 += __shfl_xor(a2, 32, 64);
    a3 += __shfl_xor(a3, 32, 64);
    rs += __shfl_xor(rs, 32, 64);
    ks += __shfl_xor(ks, 32, 64);
    ct += __shfl_xor(ct, 32, 64);
    float mk = ks / fmaxf(ct, 1.0f);
    float rho = 1.0f / (1.0f + expf(-mk));
    float inv_rs = 1.0f / fmaxf(rs, EPSF);
    if (g == 0) {  // unique owner, non-atomic RMW; quarter-wave float4
        float4* o4 = (float4*)(out + (size_t)n * 64);
        const float4* x4 = (const float4*)(x + (size_t)n * 64);
        float4 o = o4[q];
        float4 xv = x4[q];
        o.x = fmaf(rho, o.x, fmaf(TAU, xv.x, a0 * inv_rs));
        o.y = fmaf(rho, o.y, fmaf(TAU, xv.y, a1 * inv_rs));
        o.z = fmaf(rho, o.z, fmaf(TAU, xv.z, a2 * inv_rs));
        o.w = fmaf(rho, o.w, fmaf(TAU, xv.w, a3 * inv_rs));
        o4[q] = o;
        if (q == 0) row_sum[n] = rs;   // lane 0 only
    }
}

// ---- final e-indexed pass: w_norm (coalesced) + edge_index->float, fused ----
__global__ void k_final(const int* __restrict__ ei, const float* __restrict__ w,
                        const float* __restrict__ invdeg, const float* __restrict__ row_sum,
                        const float* __restrict__ maxabs,
                        float* __restrict__ out_ei, float* __restrict__ out_wn, int E, int N) {
    int e = blockIdx.x * blockDim.x + threadIdx.x;
    if (e >= E) return;
    int r0 = ei[e], c0 = ei[E + e];
    int r = min(max(r0, 0), N - 1);
    int c = min(max(c0, 0), N - 1);
    float dt = 0.5f / (*maxabs + 1e-6f);
    float kap = 2.0f * invdeg[r] + 2.0f * invdeg[c] - 2.0f;
    float wh = fmaxf(w[e] * (1.0f - 0.5f * dt * kap), 0.0f);
    if (wh <= SEPS) wh = 0.0f;
    out_wn[e] = wh / fmaxf(row_sum[r], EPSF);
    out_ei[e] = (float)r0;
    out_ei[E + e] = (float)c0;
}

extern "C" void kernel_launch(void* const* d_in, const int* in_sizes, int n_in,
                              void* d_out, int out_size, void* d_ws, size_t ws_size,
                              hipStream_t stream) {
    (void)in_sizes; (void)n_in; (void)out_size; (void)ws_size;
    const int N = NNODES, E = NEDGES;

    const float* x      = (const float*)d_in[0];
    const int*   ei     = (const int*)d_in[1];
    const float* w      = (const float*)d_in[2];
    const float* Wself  = (const float*)d_in[3];
    const float* Wneigh = (const float*)d_in[4];

    float* out    = (float*)d_out;           // [N*64]
    float* out_ei = out + (size_t)N * DIM;   // [2E] edge_index as float (final)
    float* out_wn = out_ei + 2 * (size_t)E;  // [E]  w_norm (final)

    // Statically CAP-strided bucket arena staged in out_ei/out_wn region
    // (256*7168*8B = 14.7 MB < 19.2 MB; dead until k_final overwrites it)
    ull*  arena = (ull*)out_ei;    // k_bin output: packed records
    int2* csr   = (int2*)out_ei;   // k_sort output: {col, w_e}

    // ws layout (floats): invdeg[N] | off[N] | degi[N] | row_sum[N] |
    // maxabs[4] | bcur[256] | pad-to-128B | hneigh_h u16[64N]
    // hneigh_h byte offset = (4N + 288)*4 = 1,601,152 = 128*12509 (128B-ALIGNED:
    // 64B-misaligned hneigh_h doubles gather FETCH, 99.6->178 MB, R7 lesson)
    float* invdeg  = (float*)d_ws;
    int*   off     = (int*)d_ws + (size_t)N;
    int*   degi    = (int*)d_ws + 2 * (size_t)N;
    float* row_sum = (float*)d_ws + 3 * (size_t)N;
    float* maxabs  = row_sum + (size_t)N;            // 4N
    int*   bcur    = (int*)(maxabs + 4);
    u16*   hneigh_h = (u16*)((float*)d_ws + 4 * (size_t)N + 288);

    k_init<<<1, 256, 0, stream>>>(bcur, maxabs);
    k_bin<<<(E + TILE - 1) / TILE, 256, 0, stream>>>(ei, w, bcur, arena, E, N);
    k_sort<<<K, 256, 0, stream>>>(bcur, arena, invdeg, off, degi, N);
    k_maxk<<<MAXK_GRID, 256, 0, stream>>>(ei, invdeg, maxabs, E, N);
    k_gemm<<<(N + 63) / 64, 256, 0, stream>>>(x, Wself, Wneigh, hneigh_h, out, N);
    k_aggr<<<(N + 3) / 4, 256, 0, stream>>>(off, degi, invdeg, csr, maxabs, x,
                                            hneigh_h, row_sum, out, N);
    k_final<<<(E + 255) / 256, 256, 0, stream>>>(ei, w, invdeg, row_sum, maxabs,
                                                 out_ei, out_wn, E, N);
}

// Round 11
// 243.121 us; speedup vs baseline: 1.1076x; 1.0260x over previous
//
#include <hip/hip_runtime.h>
#include <math.h>

#define NNODES 100000
#define NEDGES 1600000
#define DIM 64
#define TAU 0.5f
#define EPSF 1e-12f
#define SEPS 1e-6f

#define K 256                           // buckets
#define RPB 391                         // rows per bucket (391*256 >= 100000)
#define TILE 4096                       // edges per k_bin block
#define EPT 8                           // edges per thread in k_bin (512 thr)
#define CAP 7168                        // bucket arena stride (mean 6256, +11.6 sigma)
#define MAXK_GRID 512                   // k_maxk blocks (512 atomics total)

typedef unsigned long long ull;
typedef unsigned short u16;
typedef __attribute__((ext_vector_type(8))) short bf16x8;
typedef __attribute__((ext_vector_type(4))) float f32x4;

__device__ __forceinline__ float bf2f(u16 h) {
    return __uint_as_float((unsigned)h << 16);
}
__device__ __forceinline__ u16 f2bf(float f) {
    unsigned u = __float_as_uint(f);
    u += 0x7FFFu + ((u >> 16) & 1);  // round-to-nearest-even
    return (u16)(u >> 16);
}

// ---- init: bucket cursors to static arena bases (b*CAP); zero maxabs ----
__global__ __launch_bounds__(256) void k_init(int* __restrict__ bcur,
                                              float* __restrict__ maxabs) {
    bcur[threadIdx.x] = threadIdx.x * CAP;
    if (threadIdx.x < 4) maxabs[threadIdx.x] = 0.0f;
}

// ---- binning: 512 threads (24 waves/CU). Register-staged; one global read
//      of (r,c,w); records {w:32 | lrow:9 | col:17} bucket-sorted into LDS;
//      cooperative flush into statically-strided bucket arenas. ----
__global__ __launch_bounds__(512) void k_bin(const int* __restrict__ ei, const float* __restrict__ w,
                                             int* __restrict__ bcur, ull* __restrict__ arena,
                                             int E, int N) {
    __shared__ ull stg[TILE];
    __shared__ unsigned char bkt[TILE];
    __shared__ int cnt[K], lscan[K], gbase[K], cur[K], sc[K];
    __shared__ int tot;
    int t = threadIdx.x;
    int e0 = blockIdx.x * TILE;
    if (t < K) { cnt[t] = 0; cur[t] = 0; }
    __syncthreads();
    ull rec[EPT];
    int bb[EPT];
#pragma unroll
    for (int j = 0; j < EPT; j++) {  // independent loads in flight
        int e = e0 + t + j * 512;
        bb[j] = -1;
        if (e < E) {
            int r = min(max(ei[e], 0), N - 1);
            int c = min(max(ei[E + e], 0), N - 1);
            float wv = w[e];
            int b = r / RPB, lr = r - b * RPB;
            rec[j] = ((ull)__float_as_uint(wv) << 32) | (unsigned)(c | (lr << 17));
            bb[j] = b;
            atomicAdd(&cnt[b], 1);
        }
    }
    __syncthreads();
    int v = (t < K) ? cnt[t] : 0;
    if (t < K) sc[t] = v;
    __syncthreads();
    for (int o = 1; o < K; o <<= 1) {
        int a = (t >= o && t < K) ? sc[t - o] : 0;
        __syncthreads();
        if (t < K) sc[t] += a;
        __syncthreads();
    }
    if (t < K) {
        lscan[t] = sc[t] - v;
        if (v > 0) gbase[t] = atomicAdd(&bcur[t], v);  // one reservation per (block,bucket)
        if (t == K - 1) tot = sc[t];
    }
    __syncthreads();
#pragma unroll
    for (int j = 0; j < EPT; j++) {
        if (bb[j] >= 0) {
            int p = lscan[bb[j]] + atomicAdd(&cur[bb[j]], 1);
            stg[p] = rec[j];
            bkt[p] = (unsigned char)bb[j];
        }
    }
    __syncthreads();
    // cooperative flush: all threads stream bucket-sorted records; contiguous
    // per-bucket runs keep wave writes mostly coalesced. Overflow-guarded.
    int T = tot;
    for (int i = t; i < T; i += 512) {
        int b = bkt[i];
        size_t pos = (size_t)gbase[b] + (i - lscan[b]);
        if (pos < (size_t)(b + 1) * CAP) arena[pos] = stg[i];
    }
}

// ---- per-bucket counting sort: 512 threads (8 waves/CU, was 4).
//      Computes deg per row -> invdeg[], off[], degi[], row-sorted {col,w}. ----
__global__ __launch_bounds__(512) void k_sort(const int* __restrict__ bcur,
                                              ull* __restrict__ arena,
                                              float* __restrict__ invdeg,
                                              int* __restrict__ off, int* __restrict__ degi,
                                              int N) {
    __shared__ ull stg[CAP];
    __shared__ int hist[RPB];     // counts, then reused as local exclusive scan
    __shared__ float degl[RPB];
    __shared__ int cur[RPB];
    __shared__ int sc[512];
    int t = threadIdx.x, b = blockIdx.x;
    int base = b * CAP;
    int cnt = min(bcur[b] - base, CAP);
    for (int i = t; i < RPB; i += 512) { hist[i] = 0; degl[i] = 0.0f; cur[i] = 0; }
    __syncthreads();
    for (int i = t; i < cnt; i += 512) {
        ull rec = arena[base + i];
        stg[i] = rec;
        int lr = (int)((rec >> 17) & 0x1FF);
        atomicAdd(&hist[lr], 1);
        atomicAdd(&degl[lr], __uint_as_float((unsigned)(rec >> 32)));
    }
    __syncthreads();
    // 512-wide Hillis-Steele scan, one element per thread
    int v = (t < RPB) ? hist[t] : 0;
    sc[t] = v;
    __syncthreads();
    for (int o = 1; o < 512; o <<= 1) {
        int a = (t >= o) ? sc[t - o] : 0;
        __syncthreads();
        sc[t] += a;
        __syncthreads();
    }
    int ex = sc[t] - v;
    if (t < RPB) {
        hist[t] = ex;                    // reuse hist as lscan
        int rn = b * RPB + t;
        if (rn < N) {
            off[rn] = base + ex; degi[rn] = v;
            invdeg[rn] = 1.0f / fmaxf(degl[t], EPSF);
        }
    }
    __syncthreads();
    // scatter in place (writes land in this block's hot ~50KB L2 region)
    int2* out2 = (int2*)arena;
    for (int i = t; i < cnt; i += 512) {
        ull rec = stg[i];
        int lr = (int)((rec >> 17) & 0x1FF);
        int p = hist[lr] + atomicAdd(&cur[lr], 1);
        out2[base + p] = make_int2((int)(rec & 0x1FFFF), (int)(unsigned)(rec >> 32));
    }
}

// ---- max|kappa|: grid-stride edge scan; ONE atomic per block (512 total). ----
__global__ __launch_bounds__(256) void k_maxk(const int* __restrict__ ei,
                                              const float* __restrict__ invdeg,
                                              float* __restrict__ maxabs, int E, int N) {
    float m = 0.0f;
    int stride = gridDim.x * 256;
    for (int e = blockIdx.x * 256 + threadIdx.x; e < E; e += stride) {
        int r = min(max(ei[e], 0), N - 1);
        int c = min(max(ei[E + e], 0), N - 1);
        m = fmaxf(m, fabsf(2.0f * invdeg[r] + 2.0f * invdeg[c] - 2.0f));
    }
    for (int o = 32; o > 0; o >>= 1) m = fmaxf(m, __shfl_down(m, o, 64));
    __shared__ float red[4];
    int lane = threadIdx.x & 63, wid = threadIdx.x >> 6;
    if (lane == 0) red[wid] = m;
    __syncthreads();
    if (threadIdx.x == 0) {
        float bm = fmaxf(fmaxf(red[0], red[1]), fmaxf(red[2], red[3]));
        atomicMax((unsigned int*)maxabs, __float_as_uint(bm));  // non-negative floats
    }
}

// ---- MFMA GEMM: hneigh = x@Wn^T (bf16 store); out = x@Ws^T RAW (rho and
//      TAU*x applied later in k_aggr). Split-bf16 hi/lo -> fp32-class. ----
#define WL(mp, d, kk) (((mp) * 64 + (d)) * 72 + (kk))
__global__ __launch_bounds__(256) void k_gemm(const float* __restrict__ x,
                                              const float* __restrict__ Wself,
                                              const float* __restrict__ Wneigh,
                                              u16* __restrict__ hneigh_h,
                                              float* __restrict__ out, int N) {
    __shared__ u16 wlds[4 * 64 * 72];   // [mat*2+part][64][72], 36.9 KB
    int t = threadIdx.x;
    for (int i = t; i < 4096; i += 256) {
        int d = i >> 6, k = i & 63;
        float v = Wself[i];
        u16 h = f2bf(v);
        u16 lo = f2bf(v - bf2f(h));      // exact residual (Sterbenz)
        wlds[WL(0, d, k)] = h;
        wlds[WL(1, d, k)] = lo;
        v = Wneigh[i];
        h = f2bf(v);
        lo = f2bf(v - bf2f(h));
        wlds[WL(2, d, k)] = h;
        wlds[WL(3, d, k)] = lo;
    }
    __syncthreads();
    int w = t >> 6, l = t & 63;
    int m = l & 15, kg = l >> 4;         // A row / B col = m; k-group = kg
    int n0 = blockIdx.x * 64 + w * 16;
    if (n0 >= N) return;                 // whole-wave OOB (no barriers below)
    int nodeA = n0 + m;
    // A fragments: x row nodeA, 8 contiguous k per lane, split hi/lo
    bf16x8 ah[2], al[2];
#pragma unroll
    for (int ks = 0; ks < 2; ks++) {
        float v[8];
        if (nodeA < N) {
            const float4* xp = (const float4*)(x + (size_t)nodeA * 64 + ks * 32 + kg * 8);
            float4 v0 = xp[0], v1 = xp[1];
            v[0] = v0.x; v[1] = v0.y; v[2] = v0.z; v[3] = v0.w;
            v[4] = v1.x; v[5] = v1.y; v[6] = v1.z; v[7] = v1.w;
        } else {
#pragma unroll
            for (int j = 0; j < 8; j++) v[j] = 0.0f;
        }
#pragma unroll
        for (int j = 0; j < 8; j++) {
            u16 h = f2bf(v[j]);
            u16 lo = f2bf(v[j] - bf2f(h));
            ah[ks][j] = (short)h;
            al[ks][j] = (short)lo;
        }
    }
    f32x4 accS[4], accN[4];
#pragma unroll
    for (int dt = 0; dt < 4; dt++) {
        accS[dt] = (f32x4){0.0f, 0.0f, 0.0f, 0.0f};
        accN[dt] = (f32x4){0.0f, 0.0f, 0.0f, 0.0f};
    }
#pragma unroll
    for (int dt = 0; dt < 4; dt++) {
        int d = dt * 16 + m;
#pragma unroll
        for (int ks = 0; ks < 2; ks++) {
            int kof = ks * 32 + kg * 8;
            bf16x8 bsh = *(const bf16x8*)&wlds[WL(0, d, kof)];
            bf16x8 bsl = *(const bf16x8*)&wlds[WL(1, d, kof)];
            bf16x8 bnh = *(const bf16x8*)&wlds[WL(2, d, kof)];
            bf16x8 bnl = *(const bf16x8*)&wlds[WL(3, d, kof)];
            accS[dt] = __builtin_amdgcn_mfma_f32_16x16x32_bf16(ah[ks], bsh, accS[dt], 0, 0, 0);
            accS[dt] = __builtin_amdgcn_mfma_f32_16x16x32_bf16(al[ks], bsh, accS[dt], 0, 0, 0);
            accS[dt] = __builtin_amdgcn_mfma_f32_16x16x32_bf16(ah[ks], bsl, accS[dt], 0, 0, 0);
            accN[dt] = __builtin_amdgcn_mfma_f32_16x16x32_bf16(ah[ks], bnh, accN[dt], 0, 0, 0);
            accN[dt] = __builtin_amdgcn_mfma_f32_16x16x32_bf16(al[ks], bnh, accN[dt], 0, 0, 0);
            accN[dt] = __builtin_amdgcn_mfma_f32_16x16x32_bf16(ah[ks], bnl, accN[dt], 0, 0, 0);
        }
    }
    // epilogue: C row = kg*4 + r (node), col = m (dim within d-tile)
    int rbase = kg * 4;
#pragma unroll
    for (int r = 0; r < 4; r++) {
        int nn = n0 + rbase + r;
        if (nn >= N) continue;
#pragma unroll
        for (int dt = 0; dt < 4; dt++) {
            int d = dt * 16 + m;
            size_t idx = (size_t)nn * 64 + d;
            out[idx] = accS[dt][r];
            hneigh_h[idx] = f2bf(accN[dt][r]);
        }
    }
}

// ---- FUSED aggregation + node pass: wave per node. Inline wh (invdeg
//      gathers), acc fmas, AND rs/ks/ct reductions in one CSR walk.
//      rho/inv_rs derived in-register; epilogue applies
//      out = rho*h_self + TAU*x + acc*inv_rs; writes row_sum for k_final. ----
__global__ __launch_bounds__(256) void k_aggr(const int* __restrict__ off,
                                              const int* __restrict__ degi,
                                              const float* __restrict__ invdeg,
                                              const int2* __restrict__ csr,
                                              const float* __restrict__ maxabs,
                                              const float* __restrict__ x,
                                              const u16* __restrict__ hneigh_h,
                                              float* __restrict__ row_sum,
                                              float* __restrict__ out, int N) {
    int t = threadIdx.x;
    int lane = t & 63;
    int q = lane & 15;        // dim quad: dims 4q..4q+3
    int g = lane >> 4;        // edge sub-group 0..3
    int n = blockIdx.x * 4 + (t >> 6);
    if (n >= N) return;
    int s = off[n], end = s + degi[n];
    float dt = 0.5f / (*maxabs + 1e-6f);
    float c1 = -0.5f * dt;
    float a = 2.0f * invdeg[n] - 2.0f;
    const ushort4* hn4 = (const ushort4*)hneigh_h;
    float a0 = 0.0f, a1 = 0.0f, a2 = 0.0f, a3 = 0.0f;
    float rs = 0.0f, ks = 0.0f, ct = 0.0f;
    int i = s;
    for (; i + 16 <= end; i += 16) {  // 4 packets: 4 gathers in flight
        int2 p0 = csr[i + g];
        int2 p1 = csr[i + 4 + g];
        int2 p2 = csr[i + 8 + g];
        int2 p3 = csr[i + 12 + g];
        ushort4 h0 = hn4[(unsigned)((p0.x << 4) | q)];
        ushort4 h1 = hn4[(unsigned)((p1.x << 4) | q)];
        ushort4 h2 = hn4[(unsigned)((p2.x << 4) | q)];
        ushort4 h3 = hn4[(unsigned)((p3.x << 4) | q)];
        float k0 = fmaf(2.0f, invdeg[p0.x], a), k1 = fmaf(2.0f, invdeg[p1.x], a);
        float k2 = fmaf(2.0f, invdeg[p2.x], a), k3 = fmaf(2.0f, invdeg[p3.x], a);
        float w0 = __int_as_float(p0.y) * fmaf(c1, k0, 1.0f);
        float w1 = __int_as_float(p1.y) * fmaf(c1, k1, 1.0f);
        float w2 = __int_as_float(p2.y) * fmaf(c1, k2, 1.0f);
        float w3 = __int_as_float(p3.y) * fmaf(c1, k3, 1.0f);
        bool m0 = w0 > SEPS, m1 = w1 > SEPS, m2 = w2 > SEPS, m3 = w3 > SEPS;
        w0 = m0 ? w0 : 0.0f;
        w1 = m1 ? w1 : 0.0f;
        w2 = m2 ? w2 : 0.0f;
        w3 = m3 ? w3 : 0.0f;
        rs += (w0 + w1) + (w2 + w3);
        ks += ((m0 ? k0 : 0.0f) + (m1 ? k1 : 0.0f)) + ((m2 ? k2 : 0.0f) + (m3 ? k3 : 0.0f));
        ct += ((m0 ? 1.0f : 0.0f) + (m1 ? 1.0f : 0.0f)) + ((m2 ? 1.0f : 0.0f) + (m3 ? 1.0f : 0.0f));
        a0 = fmaf(w0, bf2f(h0.x), a0); a1 = fmaf(w0, bf2f(h0.y), a1);
        a2 = fmaf(w0, bf2f(h0.z), a2); a3 = fmaf(w0, bf2f(h0.w), a3);
        a0 = fmaf(w1, bf2f(h1.x), a0); a1 = fmaf(w1, bf2f(h1.y), a1);
        a2 = fmaf(w1, bf2f(h1.z), a2); a3 = fmaf(w1, bf2f(h1.w), a3);
        a0 = fmaf(w2, bf2f(h2.x), a0); a1 = fmaf(w2, bf2f(h2.y), a1);
        a2 = fmaf(w2, bf2f(h2.z), a2); a3 = fmaf(w2, bf2f(h2.w), a3);
        a0 = fmaf(w3, bf2f(h3.x), a0); a1 = fmaf(w3, bf2f(h3.y), a1);
        a2 = fmaf(w3, bf2f(h3.z), a2); a3 = fmaf(w3, bf2f(h3.w), a3);
    }
    for (; i < end; i += 4) {  // predicated tail, 4 edges/iter
        int e = i + g;
        bool v = e < end;
        int2 p = make_int2(0, 0);
        if (v) p = csr[e];
        ushort4 h = hn4[(unsigned)((p.x << 4) | q)];  // p.x==0 safe when masked
        float kk = fmaf(2.0f, invdeg[p.x], a);
        float wv = __int_as_float(p.y) * fmaf(c1, kk, 1.0f);
        bool m = v && (wv > SEPS);
        wv = m ? wv : 0.0f;
        rs += wv;
        ks += m ? kk : 0.0f;
        ct += m ? 1.0f : 0.0f;
        a0 = fmaf(wv, bf2f(h.x), a0);
        a1 = fmaf(wv, bf2f(h.y), a1);
        a2 = fmaf(wv, bf2f(h.z), a2);
        a3 = fmaf(wv, bf2f(h.w), a3);
    }
    // combine the 4 edge-group partials (bits 4,5 = g; q preserved)
    a0 += __shfl_xor(a0, 16, 64);
    a1 += __shfl_xor(a1, 16, 64);
    a2 += __shfl_xor(a2, 16, 64);
    a3 += __shfl_xor(a3, 16, 64);
    rs += __shfl_xor(rs, 16, 64);
    ks += __shfl_xor(ks, 16, 64);
    ct += __shfl_xor(ct, 16, 64);
    a0 += __shfl_xor(a0, 32, 64);
    a1 += __shfl_xor(a1, 32, 64);
    a2 += __shfl_xor(a2, 32, 64);
    a3 += __shfl_xor(a3, 32, 64);
    rs += __shfl_xor(rs, 32, 64);
    ks += __shfl_xor(ks, 32, 64);
    ct += __shfl_xor(ct, 32, 64);
    float mk = ks / fmaxf(ct, 1.0f);
    float rho = 1.0f / (1.0f + expf(-mk));
    float inv_rs = 1.0f / fmaxf(rs, EPSF);
    if (g == 0) {  // unique owner, non-atomic RMW; quarter-wave float4
        float4* o4 = (float4*)(out + (size_t)n * 64);
        const float4* x4 = (const float4*)(x + (size_t)n * 64);
        float4 o = o4[q];
        float4 xv = x4[q];
        o.x = fmaf(rho, o.x, fmaf(TAU, xv.x, a0 * inv_rs));
        o.y = fmaf(rho, o.y, fmaf(TAU, xv.y, a1 * inv_rs));
        o.z = fmaf(rho, o.z, fmaf(TAU, xv.z, a2 * inv_rs));
        o.w = fmaf(rho, o.w, fmaf(TAU, xv.w, a3 * inv_rs));
        o4[q] = o;
        if (q == 0) row_sum[n] = rs;   // lane 0 only
    }
}

// ---- final e-indexed pass: w_norm (coalesced) + edge_index->float, fused ----
__global__ void k_final(const int* __restrict__ ei, const float* __restrict__ w,
                        const float* __restrict__ invdeg, const float* __restrict__ row_sum,
                        const float* __restrict__ maxabs,
                        float* __restrict__ out_ei, float* __restrict__ out_wn, int E, int N) {
    int e = blockIdx.x * blockDim.x + threadIdx.x;
    if (e >= E) return;
    int r0 = ei[e], c0 = ei[E + e];
    int r = min(max(r0, 0), N - 1);
    int c = min(max(c0, 0), N - 1);
    float dt = 0.5f / (*maxabs + 1e-6f);
    float kap = 2.0f * invdeg[r] + 2.0f * invdeg[c] - 2.0f;
    float wh = fmaxf(w[e] * (1.0f - 0.5f * dt * kap), 0.0f);
    if (wh <= SEPS) wh = 0.0f;
    out_wn[e] = wh / fmaxf(row_sum[r], EPSF);
    out_ei[e] = (float)r0;
    out_ei[E + e] = (float)c0;
}

extern "C" void kernel_launch(void* const* d_in, const int* in_sizes, int n_in,
                              void* d_out, int out_size, void* d_ws, size_t ws_size,
                              hipStream_t stream) {
    (void)in_sizes; (void)n_in; (void)out_size; (void)ws_size;
    const int N = NNODES, E = NEDGES;

    const float* x      = (const float*)d_in[0];
    const int*   ei     = (const int*)d_in[1];
    const float* w      = (const float*)d_in[2];
    const float* Wself  = (const float*)d_in[3];
    const float* Wneigh = (const float*)d_in[4];

    float* out    = (float*)d_out;           // [N*64]
    float* out_ei = out + (size_t)N * DIM;   // [2E] edge_index as float (final)
    float* out_wn = out_ei + 2 * (size_t)E;  // [E]  w_norm (final)

    // Statically CAP-strided bucket arena staged in out_ei/out_wn region
    // (256*7168*8B = 14.7 MB < 19.2 MB; dead until k_final overwrites it)
    ull*  arena = (ull*)out_ei;    // k_bin output: packed records
    int2* csr   = (int2*)out_ei;   // k_sort output: {col, w_e}

    // ws layout (floats): invdeg[N] | off[N] | degi[N] | row_sum[N] |
    // maxabs[4] | bcur[256] | pad-to-128B | hneigh_h u16[64N]
    // hneigh_h byte offset = (4N + 288)*4 = 1,601,152 = 128*12509 (128B-ALIGNED:
    // 64B-misaligned hneigh_h doubles gather FETCH, 99.6->178 MB, R7 lesson)
    float* invdeg  = (float*)d_ws;
    int*   off     = (int*)d_ws + (size_t)N;
    int*   degi    = (int*)d_ws + 2 * (size_t)N;
    float* row_sum = (float*)d_ws + 3 * (size_t)N;
    float* maxabs  = row_sum + (size_t)N;            // 4N
    int*   bcur    = (int*)(maxabs + 4);
    u16*   hneigh_h = (u16*)((float*)d_ws + 4 * (size_t)N + 288);

    k_init<<<1, 256, 0, stream>>>(bcur, maxabs);
    k_bin<<<(E + TILE - 1) / TILE, 512, 0, stream>>>(ei, w, bcur, arena, E, N);
    k_sort<<<K, 512, 0, stream>>>(bcur, arena, invdeg, off, degi, N);
    k_maxk<<<MAXK_GRID, 256, 0, stream>>>(ei, invdeg, maxabs, E, N);
    k_gemm<<<(N + 63) / 64, 256, 0, stream>>>(x, Wself, Wneigh, hneigh_h, out, N);
    k_aggr<<<(N + 3) / 4, 256, 0, stream>>>(off, degi, invdeg, csr, maxabs, x,
                                            hneigh_h, row_sum, out, N);
    k_final<<<(E + 255) / 256, 256, 0, stream>>>(ei, w, invdeg, row_sum, maxabs,
                                                 out_ei, out_wn, E, N);
}

// Round 12
// 238.501 us; speedup vs baseline: 1.1291x; 1.0194x over previous
//
#include <hip/hip_runtime.h>
#include <math.h>

#define NNODES 100000
#define NEDGES 1600000
#define DIM 64
#define TAU 0.5f
#define EPSF 1e-12f
#define SEPS 1e-6f

#define K 256                           // buckets
#define RPB 391                         // rows per bucket (391*256 >= 100000)
#define TILE 4096                       // edges per k_bin block
#define EPT 8                           // edges per thread in k_bin (512 thr)
#define CAP 7168                        // bucket arena stride (mean 6256, +11.6 sigma)
#define MAXK_GRID 512                   // k_maxk blocks (512 atomics total)
#define GEMM_BLKS ((NNODES + 127) / 128)  // 128 nodes per 512-thr gemm block

typedef unsigned long long ull;
typedef unsigned short u16;
typedef __attribute__((ext_vector_type(8))) short bf16x8;
typedef __attribute__((ext_vector_type(4))) float f32x4;

__device__ __forceinline__ float bf2f(u16 h) {
    return __uint_as_float((unsigned)h << 16);
}
__device__ __forceinline__ u16 f2bf(float f) {
    unsigned u = __float_as_uint(f);
    u += 0x7FFFu + ((u >> 16) & 1);  // round-to-nearest-even
    return (u16)(u >> 16);
}

// ---- init: bucket cursors to static arena bases (b*CAP); zero maxabs ----
__global__ __launch_bounds__(256) void k_init(int* __restrict__ bcur,
                                              float* __restrict__ maxabs) {
    bcur[threadIdx.x] = threadIdx.x * CAP;
    if (threadIdx.x < 4) maxabs[threadIdx.x] = 0.0f;
}

// ---- binning: 512 threads. Register-staged; one global read of (r,c,w);
//      records {w:32 | lrow:9 | col:17} bucket-sorted into LDS; cooperative
//      flush into statically-strided bucket arenas. ----
__global__ __launch_bounds__(512) void k_bin(const int* __restrict__ ei, const float* __restrict__ w,
                                             int* __restrict__ bcur, ull* __restrict__ arena,
                                             int E, int N) {
    __shared__ ull stg[TILE];
    __shared__ unsigned char bkt[TILE];
    __shared__ int cnt[K], lscan[K], gbase[K], cur[K], sc[K];
    __shared__ int tot;
    int t = threadIdx.x;
    int e0 = blockIdx.x * TILE;
    if (t < K) { cnt[t] = 0; cur[t] = 0; }
    __syncthreads();
    ull rec[EPT];
    int bb[EPT];
#pragma unroll
    for (int j = 0; j < EPT; j++) {  // independent loads in flight
        int e = e0 + t + j * 512;
        bb[j] = -1;
        if (e < E) {
            int r = min(max(ei[e], 0), N - 1);
            int c = min(max(ei[E + e], 0), N - 1);
            float wv = w[e];
            int b = r / RPB, lr = r - b * RPB;
            rec[j] = ((ull)__float_as_uint(wv) << 32) | (unsigned)(c | (lr << 17));
            bb[j] = b;
            atomicAdd(&cnt[b], 1);
        }
    }
    __syncthreads();
    int v = (t < K) ? cnt[t] : 0;
    if (t < K) sc[t] = v;
    __syncthreads();
    for (int o = 1; o < K; o <<= 1) {
        int a = (t >= o && t < K) ? sc[t - o] : 0;
        __syncthreads();
        if (t < K) sc[t] += a;
        __syncthreads();
    }
    if (t < K) {
        lscan[t] = sc[t] - v;
        if (v > 0) gbase[t] = atomicAdd(&bcur[t], v);  // one reservation per (block,bucket)
        if (t == K - 1) tot = sc[t];
    }
    __syncthreads();
#pragma unroll
    for (int j = 0; j < EPT; j++) {
        if (bb[j] >= 0) {
            int p = lscan[bb[j]] + atomicAdd(&cur[bb[j]], 1);
            stg[p] = rec[j];
            bkt[p] = (unsigned char)bb[j];
        }
    }
    __syncthreads();
    // cooperative flush: contiguous per-bucket runs, overflow-guarded
    int T = tot;
    for (int i = t; i < T; i += 512) {
        int b = bkt[i];
        size_t pos = (size_t)gbase[b] + (i - lscan[b]);
        if (pos < (size_t)(b + 1) * CAP) arena[pos] = stg[i];
    }
}

// ---- MERGED sort || gemm kernel: blocks [0,K) = per-bucket counting sort;
//      blocks [K, K+GEMM_BLKS) = MFMA GEMM (independent work; gemm backfills
//      CUs while sort blocks wait on LDS atomics). LDS is a union. ----
struct SortSmem {
    ull stg[CAP];
    int hist[RPB];
    float degl[RPB];
    int cur[RPB];
    int sc[512];
};
struct GemmSmem {
    u16 wlds[4 * 64 * 72];
};
#define WL(mp, d, kk) (((mp) * 64 + (d)) * 72 + (kk))

__global__ __launch_bounds__(512) void k_sg(const int* __restrict__ bcur,
                                            ull* __restrict__ arena,
                                            float* __restrict__ invdeg,
                                            int* __restrict__ off, int* __restrict__ degi,
                                            const float* __restrict__ x,
                                            const float* __restrict__ Wself,
                                            const float* __restrict__ Wneigh,
                                            u16* __restrict__ hneigh_h,
                                            float* __restrict__ out, int N) {
    __shared__ __align__(16) char smraw[sizeof(SortSmem)];
    int t = threadIdx.x;
    if (blockIdx.x < K) {
        // ================= SORT role =================
        SortSmem* sm = (SortSmem*)smraw;
        int b = blockIdx.x;
        int base = b * CAP;
        int cnt = min(bcur[b] - base, CAP);
        for (int i = t; i < RPB; i += 512) { sm->hist[i] = 0; sm->degl[i] = 0.0f; sm->cur[i] = 0; }
        __syncthreads();
        for (int i = t; i < cnt; i += 512) {
            ull rec = arena[base + i];
            sm->stg[i] = rec;
            int lr = (int)((rec >> 17) & 0x1FF);
            atomicAdd(&sm->hist[lr], 1);
            atomicAdd(&sm->degl[lr], __uint_as_float((unsigned)(rec >> 32)));
        }
        __syncthreads();
        int v = (t < RPB) ? sm->hist[t] : 0;
        sm->sc[t] = v;
        __syncthreads();
        for (int o = 1; o < 512; o <<= 1) {
            int a = (t >= o) ? sm->sc[t - o] : 0;
            __syncthreads();
            sm->sc[t] += a;
            __syncthreads();
        }
        int ex = sm->sc[t] - v;
        if (t < RPB) {
            sm->hist[t] = ex;                // reuse hist as lscan
            int rn = b * RPB + t;
            if (rn < N) {
                off[rn] = base + ex; degi[rn] = v;
                invdeg[rn] = 1.0f / fmaxf(sm->degl[t], EPSF);
            }
        }
        __syncthreads();
        int2* out2 = (int2*)arena;
        for (int i = t; i < cnt; i += 512) {
            ull rec = sm->stg[i];
            int lr = (int)((rec >> 17) & 0x1FF);
            int p = sm->hist[lr] + atomicAdd(&sm->cur[lr], 1);
            out2[base + p] = make_int2((int)(rec & 0x1FFFF), (int)(unsigned)(rec >> 32));
        }
    } else {
        // ================= GEMM role (512 thr, 128 nodes/block) =================
        GemmSmem* sm = (GemmSmem*)smraw;
        for (int i = t; i < 4096; i += 512) {
            int d = i >> 6, k = i & 63;
            float v = Wself[i];
            u16 h = f2bf(v);
            u16 lo = f2bf(v - bf2f(h));      // exact residual (Sterbenz)
            sm->wlds[WL(0, d, k)] = h;
            sm->wlds[WL(1, d, k)] = lo;
            v = Wneigh[i];
            h = f2bf(v);
            lo = f2bf(v - bf2f(h));
            sm->wlds[WL(2, d, k)] = h;
            sm->wlds[WL(3, d, k)] = lo;
        }
        __syncthreads();
        int w = t >> 6, l = t & 63;
        int m = l & 15, kg = l >> 4;         // A row / B col = m; k-group = kg
        int n0 = (blockIdx.x - K) * 128 + w * 16;
        if (n0 >= N) return;                 // whole-wave OOB (no barriers below)
        int nodeA = n0 + m;
        bf16x8 ah[2], al[2];
#pragma unroll
        for (int ks = 0; ks < 2; ks++) {
            float v[8];
            if (nodeA < N) {
                const float4* xp = (const float4*)(x + (size_t)nodeA * 64 + ks * 32 + kg * 8);
                float4 v0 = xp[0], v1 = xp[1];
                v[0] = v0.x; v[1] = v0.y; v[2] = v0.z; v[3] = v0.w;
                v[4] = v1.x; v[5] = v1.y; v[6] = v1.z; v[7] = v1.w;
            } else {
#pragma unroll
                for (int j = 0; j < 8; j++) v[j] = 0.0f;
            }
#pragma unroll
            for (int j = 0; j < 8; j++) {
                u16 h = f2bf(v[j]);
                u16 lo = f2bf(v[j] - bf2f(h));
                ah[ks][j] = (short)h;
                al[ks][j] = (short)lo;
            }
        }
        f32x4 accS[4], accN[4];
#pragma unroll
        for (int dt = 0; dt < 4; dt++) {
            accS[dt] = (f32x4){0.0f, 0.0f, 0.0f, 0.0f};
            accN[dt] = (f32x4){0.0f, 0.0f, 0.0f, 0.0f};
        }
#pragma unroll
        for (int dt = 0; dt < 4; dt++) {
            int d = dt * 16 + m;
#pragma unroll
            for (int ks = 0; ks < 2; ks++) {
                int kof = ks * 32 + kg * 8;
                bf16x8 bsh = *(const bf16x8*)&sm->wlds[WL(0, d, kof)];
                bf16x8 bsl = *(const bf16x8*)&sm->wlds[WL(1, d, kof)];
                bf16x8 bnh = *(const bf16x8*)&sm->wlds[WL(2, d, kof)];
                bf16x8 bnl = *(const bf16x8*)&sm->wlds[WL(3, d, kof)];
                accS[dt] = __builtin_amdgcn_mfma_f32_16x16x32_bf16(ah[ks], bsh, accS[dt], 0, 0, 0);
                accS[dt] = __builtin_amdgcn_mfma_f32_16x16x32_bf16(al[ks], bsh, accS[dt], 0, 0, 0);
                accS[dt] = __builtin_amdgcn_mfma_f32_16x16x32_bf16(ah[ks], bsl, accS[dt], 0, 0, 0);
                accN[dt] = __builtin_amdgcn_mfma_f32_16x16x32_bf16(ah[ks], bnh, accN[dt], 0, 0, 0);
                accN[dt] = __builtin_amdgcn_mfma_f32_16x16x32_bf16(al[ks], bnh, accN[dt], 0, 0, 0);
                accN[dt] = __builtin_amdgcn_mfma_f32_16x16x32_bf16(ah[ks], bnl, accN[dt], 0, 0, 0);
            }
        }
        int rbase = kg * 4;
#pragma unroll
        for (int r = 0; r < 4; r++) {
            int nn = n0 + rbase + r;
            if (nn >= N) continue;
#pragma unroll
            for (int dt = 0; dt < 4; dt++) {
                int d = dt * 16 + m;
                size_t idx = (size_t)nn * 64 + d;
                out[idx] = accS[dt][r];
                hneigh_h[idx] = f2bf(accN[dt][r]);
            }
        }
    }
}

// ---- max|kappa|: grid-stride edge scan; ONE atomic per block (512 total). ----
__global__ __launch_bounds__(256) void k_maxk(const int* __restrict__ ei,
                                              const float* __restrict__ invdeg,
                                              float* __restrict__ maxabs, int E, int N) {
    float m = 0.0f;
    int stride = gridDim.x * 256;
    for (int e = blockIdx.x * 256 + threadIdx.x; e < E; e += stride) {
        int r = min(max(ei[e], 0), N - 1);
        int c = min(max(ei[E + e], 0), N - 1);
        m = fmaxf(m, fabsf(2.0f * invdeg[r] + 2.0f * invdeg[c] - 2.0f));
    }
    for (int o = 32; o > 0; o >>= 1) m = fmaxf(m, __shfl_down(m, o, 64));
    __shared__ float red[4];
    int lane = threadIdx.x & 63, wid = threadIdx.x >> 6;
    if (lane == 0) red[wid] = m;
    __syncthreads();
    if (threadIdx.x == 0) {
        float bm = fmaxf(fmaxf(red[0], red[1]), fmaxf(red[2], red[3]));
        atomicMax((unsigned int*)maxabs, __float_as_uint(bm));  // non-negative floats
    }
}

// ---- FUSED aggregation + node pass: wave per node. Inline wh (invdeg
//      gathers), acc fmas, AND rs/ks/ct reductions in one CSR walk.
//      rho/inv_rs derived in-register; epilogue applies
//      out = rho*h_self + TAU*x + acc*inv_rs; writes row_sum for k_final. ----
__global__ __launch_bounds__(256) void k_aggr(const int* __restrict__ off,
                                              const int* __restrict__ degi,
                                              const float* __restrict__ invdeg,
                                              const int2* __restrict__ csr,
                                              const float* __restrict__ maxabs,
                                              const float* __restrict__ x,
                                              const u16* __restrict__ hneigh_h,
                                              float* __restrict__ row_sum,
                                              float* __restrict__ out, int N) {
    int t = threadIdx.x;
    int lane = t & 63;
    int q = lane & 15;        // dim quad: dims 4q..4q+3
    int g = lane >> 4;        // edge sub-group 0..3
    int n = blockIdx.x * 4 + (t >> 6);
    if (n >= N) return;
    int s = off[n], end = s + degi[n];
    float dt = 0.5f / (*maxabs + 1e-6f);
    float c1 = -0.5f * dt;
    float a = 2.0f * invdeg[n] - 2.0f;
    const ushort4* hn4 = (const ushort4*)hneigh_h;
    float a0 = 0.0f, a1 = 0.0f, a2 = 0.0f, a3 = 0.0f;
    float rs = 0.0f, ks = 0.0f, ct = 0.0f;
    int i = s;
    for (; i + 16 <= end; i += 16) {  // 4 packets: 4 gathers in flight
        int2 p0 = csr[i + g];
        int2 p1 = csr[i + 4 + g];
        int2 p2 = csr[i + 8 + g];
        int2 p3 = csr[i + 12 + g];
        ushort4 h0 = hn4[(unsigned)((p0.x << 4) | q)];
        ushort4 h1 = hn4[(unsigned)((p1.x << 4) | q)];
        ushort4 h2 = hn4[(unsigned)((p2.x << 4) | q)];
        ushort4 h3 = hn4[(unsigned)((p3.x << 4) | q)];
        float k0 = fmaf(2.0f, invdeg[p0.x], a), k1 = fmaf(2.0f, invdeg[p1.x], a);
        float k2 = fmaf(2.0f, invdeg[p2.x], a), k3 = fmaf(2.0f, invdeg[p3.x], a);
        float w0 = __int_as_float(p0.y) * fmaf(c1, k0, 1.0f);
        float w1 = __int_as_float(p1.y) * fmaf(c1, k1, 1.0f);
        float w2 = __int_as_float(p2.y) * fmaf(c1, k2, 1.0f);
        float w3 = __int_as_float(p3.y) * fmaf(c1, k3, 1.0f);
        bool m0 = w0 > SEPS, m1 = w1 > SEPS, m2 = w2 > SEPS, m3 = w3 > SEPS;
        w0 = m0 ? w0 : 0.0f;
        w1 = m1 ? w1 : 0.0f;
        w2 = m2 ? w2 : 0.0f;
        w3 = m3 ? w3 : 0.0f;
        rs += (w0 + w1) + (w2 + w3);
        ks += ((m0 ? k0 : 0.0f) + (m1 ? k1 : 0.0f)) + ((m2 ? k2 : 0.0f) + (m3 ? k3 : 0.0f));
        ct += ((m0 ? 1.0f : 0.0f) + (m1 ? 1.0f : 0.0f)) + ((m2 ? 1.0f : 0.0f) + (m3 ? 1.0f : 0.0f));
        a0 = fmaf(w0, bf2f(h0.x), a0); a1 = fmaf(w0, bf2f(h0.y), a1);
        a2 = fmaf(w0, bf2f(h0.z), a2); a3 = fmaf(w0, bf2f(h0.w), a3);
        a0 = fmaf(w1, bf2f(h1.x), a0); a1 = fmaf(w1, bf2f(h1.y), a1);
        a2 = fmaf(w1, bf2f(h1.z), a2); a3 = fmaf(w1, bf2f(h1.w), a3);
        a0 = fmaf(w2, bf2f(h2.x), a0); a1 = fmaf(w2, bf2f(h2.y), a1);
        a2 = fmaf(w2, bf2f(h2.z), a2); a3 = fmaf(w2, bf2f(h2.w), a3);
        a0 = fmaf(w3, bf2f(h3.x), a0); a1 = fmaf(w3, bf2f(h3.y), a1);
        a2 = fmaf(w3, bf2f(h3.z), a2); a3 = fmaf(w3, bf2f(h3.w), a3);
    }
    for (; i < end; i += 4) {  // predicated tail, 4 edges/iter
        int e = i + g;
        bool v = e < end;
        int2 p = make_int2(0, 0);
        if (v) p = csr[e];
        ushort4 h = hn4[(unsigned)((p.x << 4) | q)];  // p.x==0 safe when masked
        float kk = fmaf(2.0f, invdeg[p.x], a);
        float wv = __int_as_float(p.y) * fmaf(c1, kk, 1.0f);
        bool m = v && (wv > SEPS);
        wv = m ? wv : 0.0f;
        rs += wv;
        ks += m ? kk : 0.0f;
        ct += m ? 1.0f : 0.0f;
        a0 = fmaf(wv, bf2f(h.x), a0);
        a1 = fmaf(wv, bf2f(h.y), a1);
        a2 = fmaf(wv, bf2f(h.z), a2);
        a3 = fmaf(wv, bf2f(h.w), a3);
    }
    // combine the 4 edge-group partials (bits 4,5 = g; q preserved)
    a0 += __shfl_xor(a0, 16, 64);
    a1 += __shfl_xor(a1, 16, 64);
    a2 += __shfl_xor(a2, 16, 64);
    a3 += __shfl_xor(a3, 16, 64);
    rs += __shfl_xor(rs, 16, 64);
    ks += __shfl_xor(ks, 16, 64);
    ct += __shfl_xor(ct, 16, 64);
    a0 += __shfl_xor(a0, 32, 64);
    a1 += __shfl_xor(a1, 32, 64);
    a2 += __shfl_xor(a2, 32, 64);
    a3 += __shfl_xor(a3, 32, 64);
    rs += __shfl_xor(rs, 32, 64);
    ks += __shfl_xor(ks, 32, 64);
    ct += __shfl_xor(ct, 32, 64);
    float mk = ks / fmaxf(ct, 1.0f);
    float rho = 1.0f / (1.0f + expf(-mk));
    float inv_rs = 1.0f / fmaxf(rs, EPSF);
    if (g == 0) {  // unique owner, non-atomic RMW; quarter-wave float4
        float4* o4 = (float4*)(out + (size_t)n * 64);
        const float4* x4 = (const float4*)(x + (size_t)n * 64);
        float4 o = o4[q];
        float4 xv = x4[q];
        o.x = fmaf(rho, o.x, fmaf(TAU, xv.x, a0 * inv_rs));
        o.y = fmaf(rho, o.y, fmaf(TAU, xv.y, a1 * inv_rs));
        o.z = fmaf(rho, o.z, fmaf(TAU, xv.z, a2 * inv_rs));
        o.w = fmaf(rho, o.w, fmaf(TAU, xv.w, a3 * inv_rs));
        o4[q] = o;
        if (q == 0) row_sum[n] = rs;   // lane 0 only
    }
}

// ---- final e-indexed pass: w_norm (coalesced) + edge_index->float, fused ----
__global__ void k_final(const int* __restrict__ ei, const float* __restrict__ w,
                        const float* __restrict__ invdeg, const float* __restrict__ row_sum,
                        const float* __restrict__ maxabs,
                        float* __restrict__ out_ei, float* __restrict__ out_wn, int E, int N) {
    int e = blockIdx.x * blockDim.x + threadIdx.x;
    if (e >= E) return;
    int r0 = ei[e], c0 = ei[E + e];
    int r = min(max(r0, 0), N - 1);
    int c = min(max(c0, 0), N - 1);
    float dt = 0.5f / (*maxabs + 1e-6f);
    float kap = 2.0f * invdeg[r] + 2.0f * invdeg[c] - 2.0f;
    float wh = fmaxf(w[e] * (1.0f - 0.5f * dt * kap), 0.0f);
    if (wh <= SEPS) wh = 0.0f;
    out_wn[e] = wh / fmaxf(row_sum[r], EPSF);
    out_ei[e] = (float)r0;
    out_ei[E + e] = (float)c0;
}

extern "C" void kernel_launch(void* const* d_in, const int* in_sizes, int n_in,
                              void* d_out, int out_size, void* d_ws, size_t ws_size,
                              hipStream_t stream) {
    (void)in_sizes; (void)n_in; (void)out_size; (void)ws_size;
    const int N = NNODES, E = NEDGES;

    const float* x      = (const float*)d_in[0];
    const int*   ei     = (const int*)d_in[1];
    const float* w      = (const float*)d_in[2];
    const float* Wself  = (const float*)d_in[3];
    const float* Wneigh = (const float*)d_in[4];

    float* out    = (float*)d_out;           // [N*64]
    float* out_ei = out + (size_t)N * DIM;   // [2E] edge_index as float (final)
    float* out_wn = out_ei + 2 * (size_t)E;  // [E]  w_norm (final)

    // Statically CAP-strided bucket arena staged in out_ei/out_wn region
    // (256*7168*8B = 14.7 MB < 19.2 MB; dead until k_final overwrites it)
    ull*  arena = (ull*)out_ei;    // k_bin output: packed records
    int2* csr   = (int2*)out_ei;   // k_sg sort output: {col, w_e}

    // ws layout (floats): invdeg[N] | off[N] | degi[N] | row_sum[N] |
    // maxabs[4] | bcur[256] | pad-to-128B | hneigh_h u16[64N]
    // hneigh_h byte offset = (4N + 288)*4 = 1,601,152 = 128*12509 (128B-ALIGNED:
    // 64B-misaligned hneigh_h doubles gather FETCH, 99.6->178 MB, R7 lesson)
    float* invdeg  = (float*)d_ws;
    int*   off     = (int*)d_ws + (size_t)N;
    int*   degi    = (int*)d_ws + 2 * (size_t)N;
    float* row_sum = (float*)d_ws + 3 * (size_t)N;
    float* maxabs  = row_sum + (size_t)N;            // 4N
    int*   bcur    = (int*)(maxabs + 4);
    u16*   hneigh_h = (u16*)((float*)d_ws + 4 * (size_t)N + 288);

    k_init<<<1, 256, 0, stream>>>(bcur, maxabs);
    k_bin<<<(E + TILE - 1) / TILE, 512, 0, stream>>>(ei, w, bcur, arena, E, N);
    k_sg<<<K + GEMM_BLKS, 512, 0, stream>>>(bcur, arena, invdeg, off, degi,
                                            x, Wself, Wneigh, hneigh_h, out, N);
    k_maxk<<<MAXK_GRID, 256, 0, stream>>>(ei, invdeg, maxabs, E, N);
    k_aggr<<<(N + 3) / 4, 256, 0, stream>>>(off, degi, invdeg, csr, maxabs, x,
                                            hneigh_h, row_sum, out, N);
    k_final<<<(E + 255) / 256, 256, 0, stream>>>(ei, w, invdeg, row_sum, maxabs,
                                                 out_ei, out_wn, E, N);
}

// Round 13
// 238.298 us; speedup vs baseline: 1.1300x; 1.0008x over previous
//
#include <hip/hip_runtime.h>
#include <math.h>

#define NNODES 100000
#define NEDGES 1600000
#define DIM 64
#define TAU 0.5f
#define EPSF 1e-12f
#define SEPS 1e-6f

#define K 256                           // buckets
#define RPB 391                         // rows per bucket (391*256 >= 100000)
#define TILE 4096                       // edges per k_bin block
#define CAP 7168                        // bucket arena stride (mean 6256, +11.6 sigma)
#define MAXK_GRID 512                   // k_maxk blocks (512 atomics total)
#define GEMM_BLKS ((NNODES + 127) / 128)  // 128 nodes per 512-thr gemm block

typedef unsigned long long ull;
typedef unsigned short u16;
typedef __attribute__((ext_vector_type(8))) short bf16x8;
typedef __attribute__((ext_vector_type(4))) float f32x4;

__device__ __forceinline__ float bf2f(u16 h) {
    return __uint_as_float((unsigned)h << 16);
}
__device__ __forceinline__ u16 f2bf(float f) {
    unsigned u = __float_as_uint(f);
    u += 0x7FFFu + ((u >> 16) & 1);  // round-to-nearest-even
    return (u16)(u >> 16);
}

// ---- init: bucket cursors to static arena bases (b*CAP); zero maxabs ----
__global__ __launch_bounds__(256) void k_init(int* __restrict__ bcur,
                                              float* __restrict__ maxabs) {
    bcur[threadIdx.x] = threadIdx.x * CAP;
    if (threadIdx.x < 4) maxabs[threadIdx.x] = 0.0f;
}

// ---- binning: 512 threads; int4/float4 vector loads (4 edges/packet,
//      2 packets/thread). Records {w:32 | lrow:9 | col:17} bucket-sorted
//      into LDS; cooperative flush into CAP-strided bucket arenas. ----
__global__ __launch_bounds__(512) void k_bin(const int* __restrict__ ei, const float* __restrict__ w,
                                             int* __restrict__ bcur, ull* __restrict__ arena,
                                             int E, int N) {
    __shared__ ull stg[TILE];
    __shared__ unsigned char bkt[TILE];
    __shared__ int cnt[K], lscan[K], gbase[K], cur[K], sc[K];
    __shared__ int tot;
    int t = threadIdx.x;
    int e0 = blockIdx.x * TILE;
    if (t < K) { cnt[t] = 0; cur[t] = 0; }
    __syncthreads();
    ull rec[8];
    int bb[8];
    const int4* r4 = (const int4*)ei;
    const int4* c4 = (const int4*)(ei + E);
    const float4* w4 = (const float4*)w;
#pragma unroll
    for (int j2 = 0; j2 < 2; j2++) {
        int pi = t + j2 * 512;              // packet index within tile
        int be = e0 + pi * 4;               // first edge of packet
        int4 rv, cv; float4 wv;
        bool full = (be + 3 < E);
        if (full) {
            int gp = (e0 >> 2) + pi;
            rv = r4[gp]; cv = c4[gp]; wv = w4[gp];
        } else {                            // tail: guarded scalar loads
            rv = make_int4(0, 0, 0, 0); cv = rv; wv = make_float4(0, 0, 0, 0);
            if (be + 0 < E) { rv.x = ei[be];     cv.x = ei[E + be];     wv.x = w[be]; }
            if (be + 1 < E) { rv.y = ei[be + 1]; cv.y = ei[E + be + 1]; wv.y = w[be + 1]; }
            if (be + 2 < E) { rv.z = ei[be + 2]; cv.z = ei[E + be + 2]; wv.z = w[be + 2]; }
        }
        int rr[4] = {rv.x, rv.y, rv.z, rv.w};
        int cc[4] = {cv.x, cv.y, cv.z, cv.w};
        float ww[4] = {wv.x, wv.y, wv.z, wv.w};
#pragma unroll
        for (int k = 0; k < 4; k++) {
            int j = j2 * 4 + k;
            bb[j] = -1;
            if (be + k < E) {
                int r = min(max(rr[k], 0), N - 1);
                int c = min(max(cc[k], 0), N - 1);
                int b = r / RPB, lr = r - b * RPB;
                rec[j] = ((ull)__float_as_uint(ww[k]) << 32) | (unsigned)(c | (lr << 17));
                bb[j] = b;
                atomicAdd(&cnt[b], 1);
            }
        }
    }
    __syncthreads();
    int v = (t < K) ? cnt[t] : 0;
    if (t < K) sc[t] = v;
    __syncthreads();
    for (int o = 1; o < K; o <<= 1) {
        int a = (t >= o && t < K) ? sc[t - o] : 0;
        __syncthreads();
        if (t < K) sc[t] += a;
        __syncthreads();
    }
    if (t < K) {
        lscan[t] = sc[t] - v;
        if (v > 0) gbase[t] = atomicAdd(&bcur[t], v);  // one reservation per (block,bucket)
        if (t == K - 1) tot = sc[t];
    }
    __syncthreads();
#pragma unroll
    for (int j = 0; j < 8; j++) {
        if (bb[j] >= 0) {
            int p = lscan[bb[j]] + atomicAdd(&cur[bb[j]], 1);
            stg[p] = rec[j];
            bkt[p] = (unsigned char)bb[j];
        }
    }
    __syncthreads();
    // cooperative flush: contiguous per-bucket runs, overflow-guarded
    int T = tot;
    for (int i = t; i < T; i += 512) {
        int b = bkt[i];
        size_t pos = (size_t)gbase[b] + (i - lscan[b]);
        if (pos < (size_t)(b + 1) * CAP) arena[pos] = stg[i];
    }
}

// ---- MERGED sort || gemm kernel: blocks [0,K) = per-bucket counting sort;
//      blocks [K, K+GEMM_BLKS) = MFMA GEMM (independent work; gemm backfills
//      CUs while sort blocks wait on LDS atomics). LDS is a union. ----
struct SortSmem {
    ull stg[CAP];
    int hist[RPB];
    float degl[RPB];
    int cur[RPB];
    int sc[512];
};
struct GemmSmem {
    u16 wlds[4 * 64 * 72];
};
#define WL(mp, d, kk) (((mp) * 64 + (d)) * 72 + (kk))

__global__ __launch_bounds__(512) void k_sg(const int* __restrict__ bcur,
                                            ull* __restrict__ arena,
                                            float* __restrict__ invdeg,
                                            int* __restrict__ off, int* __restrict__ degi,
                                            const float* __restrict__ x,
                                            const float* __restrict__ Wself,
                                            const float* __restrict__ Wneigh,
                                            u16* __restrict__ hneigh_h,
                                            float* __restrict__ out, int N) {
    __shared__ __align__(16) char smraw[sizeof(SortSmem)];
    int t = threadIdx.x;
    if (blockIdx.x < K) {
        // ================= SORT role =================
        SortSmem* sm = (SortSmem*)smraw;
        int b = blockIdx.x;
        int base = b * CAP;
        int cnt = min(bcur[b] - base, CAP);
        for (int i = t; i < RPB; i += 512) { sm->hist[i] = 0; sm->degl[i] = 0.0f; sm->cur[i] = 0; }
        __syncthreads();
        for (int i = t; i < cnt; i += 512) {
            ull rec = arena[base + i];
            sm->stg[i] = rec;
            int lr = (int)((rec >> 17) & 0x1FF);
            atomicAdd(&sm->hist[lr], 1);
            atomicAdd(&sm->degl[lr], __uint_as_float((unsigned)(rec >> 32)));
        }
        __syncthreads();
        int v = (t < RPB) ? sm->hist[t] : 0;
        sm->sc[t] = v;
        __syncthreads();
        for (int o = 1; o < 512; o <<= 1) {
            int a = (t >= o) ? sm->sc[t - o] : 0;
            __syncthreads();
            sm->sc[t] += a;
            __syncthreads();
        }
        int ex = sm->sc[t] - v;
        if (t < RPB) {
            sm->hist[t] = ex;                // reuse hist as lscan
            int rn = b * RPB + t;
            if (rn < N) {
                off[rn] = base + ex; degi[rn] = v;
                invdeg[rn] = 1.0f / fmaxf(sm->degl[t], EPSF);
            }
        }
        __syncthreads();
        int2* out2 = (int2*)arena;
        for (int i = t; i < cnt; i += 512) {
            ull rec = sm->stg[i];
            int lr = (int)((rec >> 17) & 0x1FF);
            int p = sm->hist[lr] + atomicAdd(&sm->cur[lr], 1);
            out2[base + p] = make_int2((int)(rec & 0x1FFFF), (int)(unsigned)(rec >> 32));
        }
    } else {
        // ================= GEMM role (512 thr, 128 nodes/block) =================
        GemmSmem* sm = (GemmSmem*)smraw;
        for (int i = t; i < 4096; i += 512) {
            int d = i >> 6, k = i & 63;
            float v = Wself[i];
            u16 h = f2bf(v);
            u16 lo = f2bf(v - bf2f(h));      // exact residual (Sterbenz)
            sm->wlds[WL(0, d, k)] = h;
            sm->wlds[WL(1, d, k)] = lo;
            v = Wneigh[i];
            h = f2bf(v);
            lo = f2bf(v - bf2f(h));
            sm->wlds[WL(2, d, k)] = h;
            sm->wlds[WL(3, d, k)] = lo;
        }
        __syncthreads();
        int w = t >> 6, l = t & 63;
        int m = l & 15, kg = l >> 4;         // A row / B col = m; k-group = kg
        int n0 = (blockIdx.x - K) * 128 + w * 16;
        if (n0 >= N) return;                 // whole-wave OOB (no barriers below)
        int nodeA = n0 + m;
        bf16x8 ah[2], al[2];
#pragma unroll
        for (int ks = 0; ks < 2; ks++) {
            float v[8];
            if (nodeA < N) {
                const float4* xp = (const float4*)(x + (size_t)nodeA * 64 + ks * 32 + kg * 8);
                float4 v0 = xp[0], v1 = xp[1];
                v[0] = v0.x; v[1] = v0.y; v[2] = v0.z; v[3] = v0.w;
                v[4] = v1.x; v[5] = v1.y; v[6] = v1.z; v[7] = v1.w;
            } else {
#pragma unroll
                for (int j = 0; j < 8; j++) v[j] = 0.0f;
            }
#pragma unroll
            for (int j = 0; j < 8; j++) {
                u16 h = f2bf(v[j]);
                u16 lo = f2bf(v[j] - bf2f(h));
                ah[ks][j] = (short)h;
                al[ks][j] = (short)lo;
            }
        }
        f32x4 accS[4], accN[4];
#pragma unroll
        for (int dt = 0; dt < 4; dt++) {
            accS[dt] = (f32x4){0.0f, 0.0f, 0.0f, 0.0f};
            accN[dt] = (f32x4){0.0f, 0.0f, 0.0f, 0.0f};
        }
#pragma unroll
        for (int dt = 0; dt < 4; dt++) {
            int d = dt * 16 + m;
#pragma unroll
            for (int ks = 0; ks < 2; ks++) {
                int kof = ks * 32 + kg * 8;
                bf16x8 bsh = *(const bf16x8*)&sm->wlds[WL(0, d, kof)];
                bf16x8 bsl = *(const bf16x8*)&sm->wlds[WL(1, d, kof)];
                bf16x8 bnh = *(const bf16x8*)&sm->wlds[WL(2, d, kof)];
                bf16x8 bnl = *(const bf16x8*)&sm->wlds[WL(3, d, kof)];
                accS[dt] = __builtin_amdgcn_mfma_f32_16x16x32_bf16(ah[ks], bsh, accS[dt], 0, 0, 0);
                accS[dt] = __builtin_amdgcn_mfma_f32_16x16x32_bf16(al[ks], bsh, accS[dt], 0, 0, 0);
                accS[dt] = __builtin_amdgcn_mfma_f32_16x16x32_bf16(ah[ks], bsl, accS[dt], 0, 0, 0);
                accN[dt] = __builtin_amdgcn_mfma_f32_16x16x32_bf16(ah[ks], bnh, accN[dt], 0, 0, 0);
                accN[dt] = __builtin_amdgcn_mfma_f32_16x16x32_bf16(al[ks], bnh, accN[dt], 0, 0, 0);
                accN[dt] = __builtin_amdgcn_mfma_f32_16x16x32_bf16(ah[ks], bnl, accN[dt], 0, 0, 0);
            }
        }
        int rbase = kg * 4;
#pragma unroll
        for (int r = 0; r < 4; r++) {
            int nn = n0 + rbase + r;
            if (nn >= N) continue;
#pragma unroll
            for (int dt = 0; dt < 4; dt++) {
                int d = dt * 16 + m;
                size_t idx = (size_t)nn * 64 + d;
                out[idx] = accS[dt][r];
                hneigh_h[idx] = f2bf(accN[dt][r]);
            }
        }
    }
}

// ---- max|kappa|: grid-stride over 4-edge int4 packets; ONE atomic/block. ----
__global__ __launch_bounds__(256) void k_maxk(const int* __restrict__ ei,
                                              const float* __restrict__ invdeg,
                                              float* __restrict__ maxabs, int E, int N) {
    float m = 0.0f;
    int np = E >> 2;                    // E divisible by 4
    int stride = gridDim.x * 256;
    const int4* r4 = (const int4*)ei;
    const int4* c4 = (const int4*)(ei + E);
    for (int p = blockIdx.x * 256 + threadIdx.x; p < np; p += stride) {
        int4 r = r4[p], c = c4[p];
        float s0 = invdeg[min(max(r.x, 0), N - 1)] + invdeg[min(max(c.x, 0), N - 1)];
        float s1 = invdeg[min(max(r.y, 0), N - 1)] + invdeg[min(max(c.y, 0), N - 1)];
        float s2 = invdeg[min(max(r.z, 0), N - 1)] + invdeg[min(max(c.z, 0), N - 1)];
        float s3 = invdeg[min(max(r.w, 0), N - 1)] + invdeg[min(max(c.w, 0), N - 1)];
        m = fmaxf(m, fabsf(2.0f * s0 - 2.0f));
        m = fmaxf(m, fabsf(2.0f * s1 - 2.0f));
        m = fmaxf(m, fabsf(2.0f * s2 - 2.0f));
        m = fmaxf(m, fabsf(2.0f * s3 - 2.0f));
    }
    for (int o = 32; o > 0; o >>= 1) m = fmaxf(m, __shfl_down(m, o, 64));
    __shared__ float red[4];
    int lane = threadIdx.x & 63, wid = threadIdx.x >> 6;
    if (lane == 0) red[wid] = m;
    __syncthreads();
    if (threadIdx.x == 0) {
        float bm = fmaxf(fmaxf(red[0], red[1]), fmaxf(red[2], red[3]));
        atomicMax((unsigned int*)maxabs, __float_as_uint(bm));  // non-negative floats
    }
}

// ---- FUSED aggregation + node pass: wave per node. Inline wh (invdeg
//      gathers), acc fmas, AND rs/ks/ct reductions in one CSR walk.
//      rho/inv_rs derived in-register; epilogue applies
//      out = rho*h_self + TAU*x + acc*inv_rs; writes row_sum for k_final. ----
__global__ __launch_bounds__(256) void k_aggr(const int* __restrict__ off,
                                              const int* __restrict__ degi,
                                              const float* __restrict__ invdeg,
                                              const int2* __restrict__ csr,
                                              const float* __restrict__ maxabs,
                                              const float* __restrict__ x,
                                              const u16* __restrict__ hneigh_h,
                                              float* __restrict__ row_sum,
                                              float* __restrict__ out, int N) {
    int t = threadIdx.x;
    int lane = t & 63;
    int q = lane & 15;        // dim quad: dims 4q..4q+3
    int g = lane >> 4;        // edge sub-group 0..3
    int n = blockIdx.x * 4 + (t >> 6);
    if (n >= N) return;
    int s = off[n], end = s + degi[n];
    float dt = 0.5f / (*maxabs + 1e-6f);
    float c1 = -0.5f * dt;
    float a = 2.0f * invdeg[n] - 2.0f;
    const ushort4* hn4 = (const ushort4*)hneigh_h;
    float a0 = 0.0f, a1 = 0.0f, a2 = 0.0f, a3 = 0.0f;
    float rs = 0.0f, ks = 0.0f, ct = 0.0f;
    int i = s;
    for (; i + 16 <= end; i += 16) {  // 4 packets: 4 gathers in flight
        int2 p0 = csr[i + g];
        int2 p1 = csr[i + 4 + g];
        int2 p2 = csr[i + 8 + g];
        int2 p3 = csr[i + 12 + g];
        ushort4 h0 = hn4[(unsigned)((p0.x << 4) | q)];
        ushort4 h1 = hn4[(unsigned)((p1.x << 4) | q)];
        ushort4 h2 = hn4[(unsigned)((p2.x << 4) | q)];
        ushort4 h3 = hn4[(unsigned)((p3.x << 4) | q)];
        float k0 = fmaf(2.0f, invdeg[p0.x], a), k1 = fmaf(2.0f, invdeg[p1.x], a);
        float k2 = fmaf(2.0f, invdeg[p2.x], a), k3 = fmaf(2.0f, invdeg[p3.x], a);
        float w0 = __int_as_float(p0.y) * fmaf(c1, k0, 1.0f);
        float w1 = __int_as_float(p1.y) * fmaf(c1, k1, 1.0f);
        float w2 = __int_as_float(p2.y) * fmaf(c1, k2, 1.0f);
        float w3 = __int_as_float(p3.y) * fmaf(c1, k3, 1.0f);
        bool m0 = w0 > SEPS, m1 = w1 > SEPS, m2 = w2 > SEPS, m3 = w3 > SEPS;
        w0 = m0 ? w0 : 0.0f;
        w1 = m1 ? w1 : 0.0f;
        w2 = m2 ? w2 : 0.0f;
        w3 = m3 ? w3 : 0.0f;
        rs += (w0 + w1) + (w2 + w3);
        ks += ((m0 ? k0 : 0.0f) + (m1 ? k1 : 0.0f)) + ((m2 ? k2 : 0.0f) + (m3 ? k3 : 0.0f));
        ct += ((m0 ? 1.0f : 0.0f) + (m1 ? 1.0f : 0.0f)) + ((m2 ? 1.0f : 0.0f) + (m3 ? 1.0f : 0.0f));
        a0 = fmaf(w0, bf2f(h0.x), a0); a1 = fmaf(w0, bf2f(h0.y), a1);
        a2 = fmaf(w0, bf2f(h0.z), a2); a3 = fmaf(w0, bf2f(h0.w), a3);
        a0 = fmaf(w1, bf2f(h1.x), a0); a1 = fmaf(w1, bf2f(h1.y), a1);
        a2 = fmaf(w1, bf2f(h1.z), a2); a3 = fmaf(w1, bf2f(h1.w), a3);
        a0 = fmaf(w2, bf2f(h2.x), a0); a1 = fmaf(w2, bf2f(h2.y), a1);
        a2 = fmaf(w2, bf2f(h2.z), a2); a3 = fmaf(w2, bf2f(h2.w), a3);
        a0 = fmaf(w3, bf2f(h3.x), a0); a1 = fmaf(w3, bf2f(h3.y), a1);
        a2 = fmaf(w3, bf2f(h3.z), a2); a3 = fmaf(w3, bf2f(h3.w), a3);
    }
    for (; i < end; i += 4) {  // predicated tail, 4 edges/iter
        int e = i + g;
        bool v = e < end;
        int2 p = make_int2(0, 0);
        if (v) p = csr[e];
        ushort4 h = hn4[(unsigned)((p.x << 4) | q)];  // p.x==0 safe when masked
        float kk = fmaf(2.0f, invdeg[p.x], a);
        float wv = __int_as_float(p.y) * fmaf(c1, kk, 1.0f);
        bool m = v && (wv > SEPS);
        wv = m ? wv : 0.0f;
        rs += wv;
        ks += m ? kk : 0.0f;
        ct += m ? 1.0f : 0.0f;
        a0 = fmaf(wv, bf2f(h.x), a0);
        a1 = fmaf(wv, bf2f(h.y), a1);
        a2 = fmaf(wv, bf2f(h.z), a2);
        a3 = fmaf(wv, bf2f(h.w), a3);
    }
    // combine the 4 edge-group partials (bits 4,5 = g; q preserved)
    a0 += __shfl_xor(a0, 16, 64);
    a1 += __shfl_xor(a1, 16, 64);
    a2 += __shfl_xor(a2, 16, 64);
    a3 += __shfl_xor(a3, 16, 64);
    rs += __shfl_xor(rs, 16, 64);
    ks += __shfl_xor(ks, 16, 64);
    ct += __shfl_xor(ct, 16, 64);
    a0 += __shfl_xor(a0, 32, 64);
    a1 += __shfl_xor(a1, 32, 64);
    a2 += __shfl_xor(a2, 32, 64);
    a3 += __shfl_xor(a3, 32, 64);
    rs += __shfl_xor(rs, 32, 64);
    ks += __shfl_xor(ks, 32, 64);
    ct += __shfl_xor(ct, 32, 64);
    float mk = ks / fmaxf(ct, 1.0f);
    float rho = 1.0f / (1.0f + expf(-mk));
    float inv_rs = 1.0f / fmaxf(rs, EPSF);
    if (g == 0) {  // unique owner, non-atomic RMW; quarter-wave float4
        float4* o4 = (float4*)(out + (size_t)n * 64);
        const float4* x4 = (const float4*)(x + (size_t)n * 64);
        float4 o = o4[q];
        float4 xv = x4[q];
        o.x = fmaf(rho, o.x, fmaf(TAU, xv.x, a0 * inv_rs));
        o.y = fmaf(rho, o.y, fmaf(TAU, xv.y, a1 * inv_rs));
        o.z = fmaf(rho, o.z, fmaf(TAU, xv.z, a2 * inv_rs));
        o.w = fmaf(rho, o.w, fmaf(TAU, xv.w, a3 * inv_rs));
        o4[q] = o;
        if (q == 0) row_sum[n] = rs;   // lane 0 only
    }
}

// ---- final pass: 4 edges/thread, int4/float4 in, float4 out. ----
__global__ __launch_bounds__(256) void k_final(const int* __restrict__ ei, const float* __restrict__ w,
                                               const float* __restrict__ invdeg,
                                               const float* __restrict__ row_sum,
                                               const float* __restrict__ maxabs,
                                               float* __restrict__ out_ei, float* __restrict__ out_wn,
                                               int E, int N) {
    int p = blockIdx.x * 256 + threadIdx.x;
    int np = E >> 2;                    // E divisible by 4
    if (p >= np) return;
    int4 rv = ((const int4*)ei)[p];
    int4 cv = ((const int4*)(ei + E))[p];
    float4 wv = ((const float4*)w)[p];
    float dt = 0.5f / (*maxabs + 1e-6f);
    int rr[4] = {rv.x, rv.y, rv.z, rv.w};
    int cc[4] = {cv.x, cv.y, cv.z, cv.w};
    float ww[4] = {wv.x, wv.y, wv.z, wv.w};
    float wn[4];
#pragma unroll
    for (int k = 0; k < 4; k++) {
        int r = min(max(rr[k], 0), N - 1);
        int c = min(max(cc[k], 0), N - 1);
        float kap = 2.0f * invdeg[r] + 2.0f * invdeg[c] - 2.0f;
        float wh = fmaxf(ww[k] * (1.0f - 0.5f * dt * kap), 0.0f);
        if (wh <= SEPS) wh = 0.0f;
        wn[k] = wh / fmaxf(row_sum[r], EPSF);
    }
    ((float4*)out_wn)[p] = make_float4(wn[0], wn[1], wn[2], wn[3]);
    ((float4*)out_ei)[p] = make_float4((float)rr[0], (float)rr[1], (float)rr[2], (float)rr[3]);
    ((float4*)(out_ei + E))[p] = make_float4((float)cc[0], (float)cc[1], (float)cc[2], (float)cc[3]);
}

extern "C" void kernel_launch(void* const* d_in, const int* in_sizes, int n_in,
                              void* d_out, int out_size, void* d_ws, size_t ws_size,
                              hipStream_t stream) {
    (void)in_sizes; (void)n_in; (void)out_size; (void)ws_size;
    const int N = NNODES, E = NEDGES;

    const float* x      = (const float*)d_in[0];
    const int*   ei     = (const int*)d_in[1];
    const float* w      = (const float*)d_in[2];
    const float* Wself  = (const float*)d_in[3];
    const float* Wneigh = (const float*)d_in[4];

    float* out    = (float*)d_out;           // [N*64]
    float* out_ei = out + (size_t)N * DIM;   // [2E] edge_index as float (final)
    float* out_wn = out_ei + 2 * (size_t)E;  // [E]  w_norm (final)

    // Statically CAP-strided bucket arena staged in out_ei/out_wn region
    // (256*7168*8B = 14.7 MB < 19.2 MB; dead until k_final overwrites it)
    ull*  arena = (ull*)out_ei;    // k_bin output: packed records
    int2* csr   = (int2*)out_ei;   // k_sg sort output: {col, w_e}

    // ws layout (floats): invdeg[N] | off[N] | degi[N] | row_sum[N] |
    // maxabs[4] | bcur[256] | pad-to-128B | hneigh_h u16[64N]
    // hneigh_h byte offset = (4N + 288)*4 = 1,601,152 = 128*12509 (128B-ALIGNED:
    // 64B-misaligned hneigh_h doubles gather FETCH, 99.6->178 MB, R7 lesson)
    float* invdeg  = (float*)d_ws;
    int*   off     = (int*)d_ws + (size_t)N;
    int*   degi    = (int*)d_ws + 2 * (size_t)N;
    float* row_sum = (float*)d_ws + 3 * (size_t)N;
    float* maxabs  = row_sum + (size_t)N;            // 4N
    int*   bcur    = (int*)(maxabs + 4);
    u16*   hneigh_h = (u16*)((float*)d_ws + 4 * (size_t)N + 288);

    k_init<<<1, 256, 0, stream>>>(bcur, maxabs);
    k_bin<<<(E + TILE - 1) / TILE, 512, 0, stream>>>(ei, w, bcur, arena, E, N);
    k_sg<<<K + GEMM_BLKS, 512, 0, stream>>>(bcur, arena, invdeg, off, degi,
                                            x, Wself, Wneigh, hneigh_h, out, N);
    k_maxk<<<MAXK_GRID, 256, 0, stream>>>(ei, invdeg, maxabs, E, N);
    k_aggr<<<(N + 3) / 4, 256, 0, stream>>>(off, degi, invdeg, csr, maxabs, x,
                                            hneigh_h, row_sum, out, N);
    k_final<<<((E >> 2) + 255) / 256, 256, 0, stream>>>(ei, w, invdeg, row_sum, maxabs,
                                                        out_ei, out_wn, E, N);
}